// Round 14
// baseline (375.515 us; speedup 1.0000x reference)
//
#include <hip/hip_runtime.h>
#include <hip/hip_bf16.h>
#include <math.h>

#define NPTS 8192
#define CDIM 256
#define HDIM 128
#define NCH  32
#define CH   (NPTS / NCH)     // 256 candidates per chunk
#define QCAP 48               // qualifier LDS slots per target
#define NBKT 256

typedef __attribute__((ext_vector_type(8))) short bf16x8;
typedef __attribute__((ext_vector_type(4))) float f32x4;
typedef unsigned long long u64;

static __device__ __forceinline__ short f2bf(float f) {
  __hip_bfloat16 h = __float2bfloat16(f);
  return *reinterpret_cast<short*>(&h);
}

static __device__ __forceinline__ unsigned umed3(unsigned a, unsigned b,
                                                 unsigned c) {
  unsigned d;
  asm("v_med3_u32 %0, %1, %2, %3" : "=v"(d) : "v"(a), "v"(b), "v"(c));
  return d;
}

// Bit-exact d2 key shared by both kNN scan phases.
static __device__ __forceinline__ unsigned d2key(float4 p, float4 c) {
  float dot = fmaf(p.x, c.x, fmaf(p.y, c.y, p.z * c.z));
  float d2 = fmaf(-2.0f, dot, p.w + c.w);
  return __float_as_uint(fmaxf(d2, 0.0f));
}

static __device__ __forceinline__ int xbucket(float x) {
  int b = (int)floorf((x + 4.0f) * 32.0f);
  return min(max(b, 0), NBKT - 1);
}

static __device__ __forceinline__ u64 shfl_xor_u64(u64 v, int m) {
  unsigned lo = (unsigned)v, hi = (unsigned)(v >> 32);
  lo = (unsigned)__shfl_xor((int)lo, m);
  hi = (unsigned)__shfl_xor((int)hi, m);
  return ((u64)hi << 32) | lo;
}

#define U32INIT unsigned b0=~0u,b1=~0u,b2=~0u,b3=~0u,b4=~0u,b5=~0u,b6=~0u, \
                         b7=~0u,b8=~0u,b9=~0u,b10=~0u,b11=~0u,b12=~0u, \
                         b13=~0u,b14=~0u,b15=~0u;
#define U32CHAIN(key) { \
  b15 = umed3(b14, key, b15); b14 = umed3(b13, key, b14); \
  b13 = umed3(b12, key, b13); b12 = umed3(b11, key, b12); \
  b11 = umed3(b10, key, b11); b10 = umed3(b9,  key, b10); \
  b9  = umed3(b8,  key, b9);  b8  = umed3(b7,  key, b8);  \
  b7  = umed3(b6,  key, b7);  b6  = umed3(b5,  key, b6);  \
  b5  = umed3(b4,  key, b5);  b4  = umed3(b3,  key, b4);  \
  b3  = umed3(b2,  key, b3);  b2  = umed3(b1,  key, b2);  \
  b1  = umed3(b0,  key, b1);  b0  = min(b0, key); }

#define KSTEP(s) { bool sw_ = key < k##s; u64 t_ = k##s; \
                   k##s = sw_ ? key : t_; key = sw_ ? t_ : key; }
#define KCHAIN KSTEP(0) KSTEP(1) KSTEP(2) KSTEP(3) KSTEP(4) KSTEP(5) \
               KSTEP(6) KSTEP(7) KSTEP(8) KSTEP(9) KSTEP(10) KSTEP(11) \
               KSTEP(12) KSTEP(13) KSTEP(14) KSTEP(15)
#define KINIT u64 k0=~0ULL,k1=~0ULL,k2=~0ULL,k3=~0ULL,k4=~0ULL,k5=~0ULL, \
                  k6=~0ULL,k7=~0ULL,k8=~0ULL,k9=~0ULL,k10=~0ULL,k11=~0ULL, \
                  k12=~0ULL,k13=~0ULL,k14=~0ULL,k15=~0ULL;

// ---------------------------------------------------------------------------
// prep_all: 7 fragment-major bf16 weight conversions + zero hist/cursor.
// ---------------------------------------------------------------------------
__global__ __launch_bounds__(256) void prep_all(
    const float* __restrict__ c1W2, const float* __restrict__ c2W2,
    const float* __restrict__ c3W2, const float* __restrict__ c2W1,
    const float* __restrict__ c3W1, const float* __restrict__ hW1,
    const float* __restrict__ hW2,
    short* __restrict__ w2f1, short* __restrict__ w2f2,
    short* __restrict__ w2f3, short* __restrict__ wc2a,
    short* __restrict__ wc3a, short* __restrict__ whW1,
    short* __restrict__ whW2,
    unsigned* __restrict__ hist, unsigned* __restrict__ cursor) {
  int b = blockIdx.x, tid = threadIdx.x;
  if (b < 1280) {                 // five 256x256 weights, KS=8
    const float* W; short* wf; int rb;
    if (b < 256)       { W = c1W2; wf = w2f1; rb = b; }
    else if (b < 512)  { W = c2W2; wf = w2f2; rb = b - 256; }
    else if (b < 768)  { W = c3W2; wf = w2f3; rb = b - 512; }
    else if (b < 1024) { W = c2W1; wf = wc2a; rb = b - 768; }
    else               { W = c3W1; wf = wc3a; rb = b - 1024; }
    int t = rb * 256 + tid;
    int q = t & 7, l = (t >> 3) & 63, F = t >> 9;
    int ks = F & 7, c16 = F >> 3;
    int k = ks * 32 + ((l >> 4) << 3) + q;
    int c = c16 * 16 + (l & 15);
    wf[t] = f2bf(W[k * 256 + c]);
  } else if (b < 1408) {          // h_W1: KDIM 256, NCOLS 128
    int t = (b - 1280) * 256 + tid;
    int q = t & 7, l = (t >> 3) & 63, F = t >> 9;
    int ks = F & 7, c16 = F >> 3;
    int k = ks * 32 + ((l >> 4) << 3) + q;
    int c = c16 * 16 + (l & 15);
    whW1[t] = f2bf(hW1[k * 128 + c]);
  } else if (b < 1472) {          // h_W2: KDIM 128, NCOLS 128
    int t = (b - 1408) * 256 + tid;
    int q = t & 7, l = (t >> 3) & 63, F = t >> 9;
    int ks = F & 3, c16 = F >> 2;
    int k = ks * 32 + ((l >> 4) << 3) + q;
    int c = c16 * 16 + (l & 15);
    whW2[t] = f2bf(hW2[k * 128 + c]);
  } else {                        // zero hist + cursor
    hist[tid] = 0u;
    cursor[tid] = 0u;
  }
}

// ---------------------------------------------------------------------------
// Spatial bucket sort by x: histogram -> exclusive scan -> scatter.
// Within-bucket order is atomic-race dependent; downstream results are
// order-independent (exact selection over a scan set that always covers the
// true window).
// ---------------------------------------------------------------------------
__global__ __launch_bounds__(256) void hist_k(const float* __restrict__ pos,
                                              unsigned* __restrict__ hist) {
  int i = blockIdx.x * 256 + threadIdx.x;
  atomicAdd(&hist[xbucket(pos[3 * i])], 1u);
}

__global__ __launch_bounds__(256) void scan_k(const unsigned* __restrict__ hist,
                                              unsigned* __restrict__ base) {
  __shared__ unsigned s[NBKT];
  int t = threadIdx.x;
  unsigned h = hist[t];
  s[t] = h;
  __syncthreads();
  for (int off = 1; off < NBKT; off <<= 1) {
    unsigned v = (t >= off) ? s[t - off] : 0u;
    __syncthreads();
    s[t] += v;
    __syncthreads();
  }
  base[t] = s[t] - h;   // exclusive prefix
}

__global__ __launch_bounds__(256) void scatter_k(
    const float* __restrict__ pos, const unsigned* __restrict__ base,
    unsigned* __restrict__ cursor, int* __restrict__ sidx,
    int* __restrict__ inv, float4* __restrict__ pos4) {
  int i = blockIdx.x * 256 + threadIdx.x;
  float x = pos[3 * i], y = pos[3 * i + 1], z = pos[3 * i + 2];
  int b = xbucket(x);
  unsigned slot = base[b] + atomicAdd(&cursor[b], 1u);
  sidx[slot] = i;
  inv[i] = (int)slot;
  pos4[slot] = make_float4(x, y, z, x * x + y * y + z * z);
}

// ---------------------------------------------------------------------------
// chbnd_k: per-chunk x min/max (chunks are 256-point spans of sorted space).
// ---------------------------------------------------------------------------
__global__ __launch_bounds__(256) void chbnd_k(const float4* __restrict__ pos4,
                                               float* __restrict__ chbnd) {
  __shared__ float rmin[256], rmax[256];
  int ch = blockIdx.x, tid = threadIdx.x;
  float x = pos4[ch * CH + tid].x;
  rmin[tid] = x; rmax[tid] = x;
  __syncthreads();
  for (int off = 128; off; off >>= 1) {
    if (tid < off) {
      rmin[tid] = fminf(rmin[tid], rmin[tid + off]);
      rmax[tid] = fmaxf(rmax[tid], rmax[tid + off]);
    }
    __syncthreads();
  }
  if (tid == 0) { chbnd[2 * ch] = rmin[0]; chbnd[2 * ch + 1] = rmax[0]; }
}

// ---------------------------------------------------------------------------
// knn_fused: block = 32 consecutive sorted targets (one chunk), 8 lanes/tgt.
// Phase 1: scan chunks near->far with warm u32 med3 heaps; prune direction
//   when gap^2 > blockmax(b15)*1.0001 (b15 of any lane >= its target's true
//   16th distance since a slice's 16th >= union's 16th -> exact windowing).
// Phase 2: per-target exact 16th distance T via 8-lane shfl selection.
// Phase 3: replay the same chunks; collect qualifiers (d2 <= T) into LDS.
// Phase 4: exact (d2, orig_idx) top-16 via u64 chain + 8-lane selection.
// All control flow is block-uniform (bounds/flags from uniform data).
// ---------------------------------------------------------------------------
#define SCAN_CHUNK(chv) { \
    cand[tid] = pos4[(size_t)(chv) * CH + tid]; \
    __syncthreads(); \
    int j0_ = sl * 32; \
    for (int jj_ = 0; jj_ < 32; jj_ += 4) { \
      float4 c0_ = cand[j0_ + jj_],     c1_ = cand[j0_ + jj_ + 1]; \
      float4 c2_ = cand[j0_ + jj_ + 2], c3_ = cand[j0_ + jj_ + 3]; \
      unsigned x0_ = d2key(p, c0_), x1_ = d2key(p, c1_); \
      unsigned x2_ = d2key(p, c2_), x3_ = d2key(p, c3_); \
      U32CHAIN(x0_) U32CHAIN(x1_) U32CHAIN(x2_) U32CHAIN(x3_) \
    } \
    __syncthreads(); }

#define BLOCK_MAXB15(outv) { \
    red[tid] = b15; __syncthreads(); \
    for (int off_ = 128; off_; off_ >>= 1) { \
      if (tid < off_) red[tid] = max(red[tid], red[tid + off_]); \
      __syncthreads(); } \
    outv = red[0]; __syncthreads(); }

#define REPLAY_CHUNK(chv) { \
    cand[tid] = pos4[(size_t)(chv) * CH + tid]; \
    sj[tid] = sidx[(size_t)(chv) * CH + tid]; \
    __syncthreads(); \
    for (int jj_ = 0; jj_ < 32; ++jj_) { \
      int c_ = sl * 32 + jj_; \
      unsigned key_ = d2key(p, cand[c_]); \
      if (key_ <= T) { \
        unsigned pos_ = atomicAdd(&qcnt[tl], 1u); \
        if (pos_ < QCAP) qbuf[tl][pos_] = ((u64)key_ << 32) | (unsigned)sj[c_]; \
      } \
    } \
    __syncthreads(); }

__global__ __launch_bounds__(256) void knn_fused(
    const float4* __restrict__ pos4, const int* __restrict__ sidx,
    const int* __restrict__ inv, const float* __restrict__ chbnd,
    int* __restrict__ idx_out) {
  __shared__ float4 cand[CH];
  __shared__ int sj[CH];
  __shared__ unsigned red[256];
  __shared__ u64 qbuf[32][QCAP];
  __shared__ unsigned qcnt[32];
  __shared__ float fred[32];
  __shared__ float gb[2];

  int tid = threadIdx.x;
  int tl = tid >> 3, sl = tid & 7;          // target-local, slice
  int i = blockIdx.x * 32 + tl;
  int own = blockIdx.x >> 3;                // 8 blocks per 256-chunk
  float4 p = pos4[i];
  int lane = tid & 63;
  int gbase = lane & ~7;

  // group x-bounds over the 32 targets (tiny serial reduce)
  if (tid < 32) fred[tid] = pos4[blockIdx.x * 32 + tid].x;
  __syncthreads();
  if (tid == 0) {
    float lo = fred[0], hi = fred[0];
    for (int q = 1; q < 32; ++q) { lo = fminf(lo, fred[q]); hi = fmaxf(hi, fred[q]); }
    gb[0] = lo; gb[1] = hi;
  }
  __syncthreads();
  float tlo = gb[0], thi = gb[1];

  // ---- phase 1: pruned near->far scan ----
  U32INIT
  SCAN_CHUNK(own)
  int nl = 0, nr = 0;
  bool doneL = (own == 0), doneR = (own == NCH - 1);
  while (!doneL || !doneR) {
    unsigned bound;
    BLOCK_MAXB15(bound)
    float B = __uint_as_float(bound) * 1.0001f;   // NaN when heap not full -> no prune
    if (!doneL) {
      int ch = own - 1 - nl;
      float g = tlo - chbnd[2 * ch + 1];
      if (g > 0.0f && g * g > B) doneL = true;
      else { SCAN_CHUNK(ch) ++nl; doneL = (own - 1 - nl < 0); }
    }
    if (!doneR) {
      int ch = own + 1 + nr;
      float g = chbnd[2 * ch] - thi;
      if (g > 0.0f && g * g > B) doneR = true;
      else { SCAN_CHUNK(ch) ++nr; doneR = (own + 1 + nr >= NCH); }
    }
  }

  // ---- phase 2: per-target exact T (16th) via 8-lane selection ----
  unsigned h = b0;
  unsigned T = 0;
#pragma unroll
  for (int r = 0; r < 16; ++r) {
    unsigned m = h;
    m = min(m, (unsigned)__shfl_xor((int)m, 1));
    m = min(m, (unsigned)__shfl_xor((int)m, 2));
    m = min(m, (unsigned)__shfl_xor((int)m, 4));
    u64 ball = __ballot(h == m);
    unsigned gball = (unsigned)((ball >> gbase) & 0xFFull);
    bool adv = ((lane - gbase) == (__ffs((int)gball) - 1));
    h   = adv ? b1  : h;   b1  = adv ? b2  : b1;
    b2  = adv ? b3  : b2;  b3  = adv ? b4  : b3;
    b4  = adv ? b5  : b4;  b5  = adv ? b6  : b5;
    b6  = adv ? b7  : b6;  b7  = adv ? b8  : b7;
    b8  = adv ? b9  : b8;  b9  = adv ? b10 : b9;
    b10 = adv ? b11 : b10; b11 = adv ? b12 : b11;
    b12 = adv ? b13 : b12; b13 = adv ? b14 : b13;
    b14 = adv ? b15 : b14; b15 = adv ? 0xFFFFFFFFu : b15;
    T = m;
  }

  // ---- phase 3: replay scanned chunks, collect qualifiers into LDS ----
  if (tid < 32) qcnt[tid] = 0;
  __syncthreads();
  REPLAY_CHUNK(own)
  for (int q = 0; q < nl; ++q) REPLAY_CHUNK(own - 1 - q)
  for (int q = 0; q < nr; ++q) REPLAY_CHUNK(own + 1 + q)

  // ---- phase 4: exact (d2, orig_idx) top-16 + write ----
  int n = (int)min(qcnt[tl], (unsigned)QCAP);
  KINIT
  for (int q = sl; q < n; q += 8) {
    u64 key = qbuf[tl][q];
    if (key < k15) { KCHAIN }
  }
  u64 hh = k0;
  int* o = idx_out + (size_t)i * 16;
#pragma unroll
  for (int r = 0; r < 16; ++r) {
    u64 m = hh;
    u64 s_;
    s_ = shfl_xor_u64(m, 1); m = s_ < m ? s_ : m;
    s_ = shfl_xor_u64(m, 2); m = s_ < m ? s_ : m;
    s_ = shfl_xor_u64(m, 4); m = s_ < m ? s_ : m;
    u64 ball = __ballot(hh == m);
    unsigned gball = (unsigned)((ball >> gbase) & 0xFFull);
    bool adv = ((lane - gbase) == (__ffs((int)gball) - 1));
    hh  = adv ? k1  : hh;  k1  = adv ? k2  : k1;
    k2  = adv ? k3  : k2;  k3  = adv ? k4  : k3;
    k4  = adv ? k5  : k4;  k5  = adv ? k6  : k5;
    k6  = adv ? k7  : k6;  k7  = adv ? k8  : k7;
    k8  = adv ? k9  : k8;  k9  = adv ? k10 : k9;
    k10 = adv ? k11 : k10; k11 = adv ? k12 : k11;
    k12 = adv ? k13 : k12; k13 = adv ? k14 : k13;
    k14 = adv ? k15 : k14; k15 = adv ? ~0ULL : k15;
    if (sl == 0) o[r] = inv[(unsigned)m];
  }
}

// ---------------------------------------------------------------------------
// conv1 TU: TU[i][c] = b1[c] + p_i . (W1h[:,c] + W1p[:,c])   (sorted space)
// ---------------------------------------------------------------------------
__global__ __launch_bounds__(256) void tu1_prep(const float4* __restrict__ pos4,
                                                const float* __restrict__ W1,
                                                const float* __restrict__ b1,
                                                float* __restrict__ TU) {
  int c = threadIdx.x;
  float w0 = W1[c]       + W1[768 + c];
  float w1 = W1[256 + c] + W1[1024 + c];
  float w2 = W1[512 + c] + W1[1280 + c];
  float bv = b1[c];
#pragma unroll
  for (int r = 0; r < 4; ++r) {
    int i = blockIdx.x * 4 + r;
    float4 P = pos4[i];
    TU[(size_t)i * 256 + c] = fmaf(P.x, w0, fmaf(P.y, w1, fmaf(P.z, w2, bv)));
  }
}

// ---------------------------------------------------------------------------
// MFMA GEMM: out[M][NCOLS] = act(bf16(A[M][KDIM]) @ Wf + bias [+ p@W1p]).
// ---------------------------------------------------------------------------
template <int NCOLS, int KDIM, int ACT, int ADDP>
__global__ __launch_bounds__(256) void gemm_mfma(
    const float* __restrict__ A,
    const short* __restrict__ wf,
    const float* __restrict__ bias,
    const float4* __restrict__ pos4,
    const float* __restrict__ W1p,
    float* __restrict__ out) {
  constexpr int KS = KDIM / 32;
  constexpr int NF = NCOLS / 64;
  __shared__ __align__(16) short As[32 * KDIM];

  int tid = threadIdx.x;
  int row0 = blockIdx.x * 32;

  {
    int row = tid & 31, wq = tid >> 5;
    const float* Ar = A + (size_t)(row0 + row) * KDIM;
#pragma unroll
    for (int q = 0; q < KDIM / 64; ++q) {
      int c0 = wq * 8 + q * 64;
      float4 a = *reinterpret_cast<const float4*>(Ar + c0);
      float4 b = *reinterpret_cast<const float4*>(Ar + c0 + 4);
      bf16x8 o;
      o[0] = f2bf(a.x); o[1] = f2bf(a.y); o[2] = f2bf(a.z); o[3] = f2bf(a.w);
      o[4] = f2bf(b.x); o[5] = f2bf(b.y); o[6] = f2bf(b.z); o[7] = f2bf(b.w);
      int byte = row * (KDIM * 2) + c0 * 2;
      byte ^= (row & 7) << 4;
      *reinterpret_cast<bf16x8*>(reinterpret_cast<char*>(As) + byte) = o;
    }
  }
  __syncthreads();

  int l = tid & 63, w = tid >> 6;
  int lhi = l >> 4, llo = l & 15;
  f32x4 zero = {0.f, 0.f, 0.f, 0.f};
  f32x4 acc[2][NF];
#pragma unroll
  for (int m = 0; m < 2; ++m)
#pragma unroll
    for (int n = 0; n < NF; ++n) acc[m][n] = zero;

  const bf16x8* WfV = reinterpret_cast<const bf16x8*>(wf);
#pragma unroll
  for (int ks = 0; ks < KS; ++ks) {
    bf16x8 af[2], bfr[NF];
#pragma unroll
    for (int m = 0; m < 2; ++m) {
      int r = m * 16 + llo;
      int byte = r * (KDIM * 2) + ks * 64 + lhi * 16;
      byte ^= (r & 7) << 4;
      af[m] = *reinterpret_cast<const bf16x8*>(
          reinterpret_cast<const char*>(As) + byte);
    }
#pragma unroll
    for (int n = 0; n < NF; ++n)
      bfr[n] = WfV[((w * NF + n) * KS + ks) * 64 + l];
#pragma unroll
    for (int m = 0; m < 2; ++m)
#pragma unroll
      for (int n = 0; n < NF; ++n)
        acc[m][n] = __builtin_amdgcn_mfma_f32_16x16x32_bf16(af[m], bfr[n],
                                                            acc[m][n], 0, 0, 0);
  }

  int cc[NF];
  float bv[NF], u0[NF], u1[NF], u2[NF];
#pragma unroll
  for (int n = 0; n < NF; ++n) {
    cc[n] = (w * NF + n) * 16 + llo;
    bv[n] = bias[cc[n]];
    if constexpr (ADDP) {
      u0[n] = W1p[cc[n]];
      u1[n] = W1p[NCOLS + cc[n]];
      u2[n] = W1p[2 * NCOLS + cc[n]];
    } else { u0[n] = u1[n] = u2[n] = 0.f; }
  }
#pragma unroll
  for (int m = 0; m < 2; ++m)
#pragma unroll
    for (int j = 0; j < 4; ++j) {
      int r = row0 + m * 16 + lhi * 4 + j;
      float px = 0.f, py = 0.f, pz = 0.f;
      if constexpr (ADDP) {
        float4 P = pos4[r];
        px = P.x; py = P.y; pz = P.z;
      }
#pragma unroll
      for (int n = 0; n < NF; ++n) {
        float v = acc[m][n][j] + bv[n];
        if constexpr (ADDP) v += px * u0[n] + py * u1[n] + pz * u2[n];
        if (ACT == 1) v = fmaxf(v, 0.0f);
        out[(size_t)r * NCOLS + cc[n]] = v;
      }
    }
}

// ---------------------------------------------------------------------------
// MFMA conv: block = 4 targets (64 rows = 4 x 16 nbrs) x 256 cols, K=256.
// ---------------------------------------------------------------------------
__global__ __launch_bounds__(256) void conv_mfma(
    const float* __restrict__ TU,
    const float4* __restrict__ pos4,
    const int* __restrict__ idx,
    const float* __restrict__ W1p,
    const short* __restrict__ w2f,
    const float* __restrict__ b2,
    float* __restrict__ hout) {
  __shared__ __align__(16) short m1s[64 * 256];
  __shared__ float Ub[4][256];
  __shared__ int js[64];

  int tid = threadIdx.x;
  int t0 = blockIdx.x * 4;
  if (tid < 64) js[tid] = idx[(t0 + (tid >> 4)) * 16 + (tid & 15)];
#pragma unroll
  for (int q = 0; q < 4; ++q) {
    int e = tid + 256 * q;
    int tg = e >> 8, c = e & 255;
    float4 P = pos4[t0 + tg];
    Ub[tg][c] = P.x * W1p[c] + P.y * W1p[256 + c] + P.z * W1p[512 + c];
  }
  __syncthreads();

  {
    int row = tid & 63;
    int wq = tid >> 6;
    int jrow = js[row];
    const float* TUj = TU + (size_t)jrow * 256;
    const float* Ui = &Ub[row >> 4][0];
#pragma unroll
    for (int q = 0; q < 8; ++q) {
      int c0 = wq * 8 + q * 32;
      float4 a = *reinterpret_cast<const float4*>(TUj + c0);
      float4 b = *reinterpret_cast<const float4*>(TUj + c0 + 4);
      float4 ua = *reinterpret_cast<const float4*>(Ui + c0);
      float4 ub = *reinterpret_cast<const float4*>(Ui + c0 + 4);
      bf16x8 o;
      o[0] = f2bf(fmaxf(a.x - ua.x, 0.f));
      o[1] = f2bf(fmaxf(a.y - ua.y, 0.f));
      o[2] = f2bf(fmaxf(a.z - ua.z, 0.f));
      o[3] = f2bf(fmaxf(a.w - ua.w, 0.f));
      o[4] = f2bf(fmaxf(b.x - ub.x, 0.f));
      o[5] = f2bf(fmaxf(b.y - ub.y, 0.f));
      o[6] = f2bf(fmaxf(b.z - ub.z, 0.f));
      o[7] = f2bf(fmaxf(b.w - ub.w, 0.f));
      int byte = row * 512 + c0 * 2;
      byte ^= (row & 7) << 4;
      *reinterpret_cast<bf16x8*>(reinterpret_cast<char*>(m1s) + byte) = o;
    }
  }
  __syncthreads();

  int l = tid & 63, w = tid >> 6;
  int lhi = l >> 4, llo = l & 15;
  f32x4 zero = {0.f, 0.f, 0.f, 0.f};
  f32x4 acc[4][4];
#pragma unroll
  for (int m = 0; m < 4; ++m)
#pragma unroll
    for (int n = 0; n < 4; ++n) acc[m][n] = zero;

  const bf16x8* Wf = reinterpret_cast<const bf16x8*>(w2f);
#pragma unroll
  for (int ks = 0; ks < 8; ++ks) {
    int k0 = ks * 32;
    bf16x8 af[4], bfr[4];
#pragma unroll
    for (int m = 0; m < 4; ++m) {
      int r = m * 16 + llo;
      int byte = r * 512 + k0 * 2 + lhi * 16;
      byte ^= (r & 7) << 4;
      af[m] = *reinterpret_cast<const bf16x8*>(
          reinterpret_cast<const char*>(m1s) + byte);
    }
#pragma unroll
    for (int n = 0; n < 4; ++n)
      bfr[n] = Wf[((w * 4 + n) * 8 + ks) * 64 + l];
#pragma unroll
    for (int m = 0; m < 4; ++m)
#pragma unroll
      for (int n = 0; n < 4; ++n)
        acc[m][n] = __builtin_amdgcn_mfma_f32_16x16x32_bf16(af[m], bfr[n],
                                                            acc[m][n], 0, 0, 0);
  }

#pragma unroll
  for (int m = 0; m < 4; ++m)
#pragma unroll
    for (int n = 0; n < 4; ++n) {
      float v = fmaxf(fmaxf(acc[m][n][0], acc[m][n][1]),
                      fmaxf(acc[m][n][2], acc[m][n][3]));
      v = fmaxf(v, __shfl_xor(v, 16));
      v = fmaxf(v, __shfl_xor(v, 32));
      if (lhi == 0) {
        int c = w * 64 + n * 16 + llo;
        hout[(size_t)(t0 + m) * CDIM + c] = fmaxf(v + b2[c], 0.0f);
      }
    }
}

// ---------------------------------------------------------------------------
// Final layer: out[orig(r)] = sigmoid(h2[r] . w3 + b3); one wave per row.
// ---------------------------------------------------------------------------
__global__ __launch_bounds__(64) void final_k(const float* __restrict__ h2,
                                              const float* __restrict__ w3,
                                              const float* __restrict__ b3,
                                              const int* __restrict__ sidx,
                                              float* __restrict__ out) {
  int r = blockIdx.x, l = threadIdx.x;
  float s = h2[(size_t)r * HDIM + l] * w3[l] +
            h2[(size_t)r * HDIM + 64 + l] * w3[64 + l];
#pragma unroll
  for (int o = 32; o > 0; o >>= 1) s += __shfl_down(s, o);
  if (l == 0) out[sidx[r]] = 1.0f / (1.0f + expf(-(s + b3[0])));
}

extern "C" void kernel_launch(void* const* d_in, const int* in_sizes, int n_in,
                              void* d_out, int out_size, void* d_ws,
                              size_t ws_size, hipStream_t stream) {
  const float* pos   = (const float*)d_in[0];
  const float* c1_W1 = (const float*)d_in[1];
  const float* c1_b1 = (const float*)d_in[2];
  const float* c1_W2 = (const float*)d_in[3];
  const float* c1_b2 = (const float*)d_in[4];
  const float* c2_W1 = (const float*)d_in[5];
  const float* c2_b1 = (const float*)d_in[6];
  const float* c2_W2 = (const float*)d_in[7];
  const float* c2_b2 = (const float*)d_in[8];
  const float* c3_W1 = (const float*)d_in[9];
  const float* c3_b1 = (const float*)d_in[10];
  const float* c3_W2 = (const float*)d_in[11];
  const float* c3_b2 = (const float*)d_in[12];
  const float* h_W1  = (const float*)d_in[13];
  const float* h_b1  = (const float*)d_in[14];
  const float* h_W2  = (const float*)d_in[15];
  const float* h_b2  = (const float*)d_in[16];
  const float* h_W3  = (const float*)d_in[17];
  const float* h_b3  = (const float*)d_in[18];
  float* out = (float*)d_out;

  char* w = (char*)d_ws;
  const size_t MB = 1 << 20;
  const size_t KB = 1 << 10;
  int*      p_idx  = (int*)w;                           // 512K
  float4*   p_pos4 = (float4*)(w + 512 * KB);           // 128K
  short*    p_w2f1 = (short*)(w + 704 * KB);            // 128K
  short*    p_w2f2 = (short*)(w + 832 * KB);            // 128K
  short*    p_w2f3 = (short*)(w + 960 * KB);            // 128K
  short*    p_wc2a = (short*)(w + 1088 * KB);           // 128K
  short*    p_wc3a = (short*)(w + 1216 * KB);           // 128K
  short*    p_whW1 = (short*)(w + 1344 * KB);           // 64K
  short*    p_whW2 = (short*)(w + 1408 * KB);           // 32K
  unsigned* p_hist = (unsigned*)(w + 1440 * KB);        // 1K
  unsigned* p_base = (unsigned*)(w + 1441 * KB);        // 1K
  unsigned* p_cur  = (unsigned*)(w + 1442 * KB);        // 1K
  int*      p_sidx = (int*)(w + 1444 * KB);             // 32K
  int*      p_inv  = (int*)(w + 1476 * KB);             // 32K
  float*    p_chb  = (float*)(w + 1508 * KB);           // 256B
  float*    p_TU   = (float*)(w + 5 * MB);              // 8MB  [5,13)
  float*    p_hA   = (float*)(w + 13 * MB);             // 8MB
  float*    p_hB   = (float*)(w + 21 * MB);             // 8MB
  float*    p_c1   = (float*)(w + 5 * MB);              // 4MB  (TU dead)
  float*    p_c2   = (float*)(w + 9 * MB);              // 4MB

  // weight prep + zero sort counters
  prep_all<<<1473, 256, 0, stream>>>(
      c1_W2, c2_W2, c3_W2, c2_W1, c3_W1, h_W1, h_W2,
      p_w2f1, p_w2f2, p_w2f3, p_wc2a, p_wc3a, p_whW1, p_whW2, p_hist, p_cur);

  // spatial bucket sort (x) -> sorted-space pos4 + maps
  hist_k<<<NPTS / 256, 256, 0, stream>>>(pos, p_hist);
  scan_k<<<1, 256, 0, stream>>>(p_hist, p_base);
  scatter_k<<<NPTS / 256, 256, 0, stream>>>(pos, p_base, p_cur,
                                            p_sidx, p_inv, p_pos4);

  // conv1 TU (sorted space)
  tu1_prep<<<NPTS / 4, 256, 0, stream>>>(p_pos4, c1_W1, c1_b1, p_TU);

  // kNN: fused exact windowed top-16 (single kernel, LDS-only intermediates)
  chbnd_k<<<NCH, 256, 0, stream>>>(p_pos4, p_chb);
  knn_fused<<<NPTS / 32, 256, 0, stream>>>(p_pos4, p_sidx, p_inv, p_chb, p_idx);

  // conv1
  conv_mfma<<<NPTS / 4, 256, 0, stream>>>(p_TU, p_pos4, p_idx, c1_W1 + 3 * 256,
                                          p_w2f1, c1_b2, p_hA);
  // conv2
  gemm_mfma<256, 256, 0, 1><<<NPTS / 32, 256, 0, stream>>>(
      p_hA, p_wc2a, c2_b1, p_pos4, c2_W1 + 256 * 256, p_TU);
  conv_mfma<<<NPTS / 4, 256, 0, stream>>>(p_TU, p_pos4, p_idx,
                                          c2_W1 + 256 * 256, p_w2f2, c2_b2, p_hB);
  // conv3
  gemm_mfma<256, 256, 0, 1><<<NPTS / 32, 256, 0, stream>>>(
      p_hB, p_wc3a, c3_b1, p_pos4, c3_W1 + 256 * 256, p_TU);
  conv_mfma<<<NPTS / 4, 256, 0, stream>>>(p_TU, p_pos4, p_idx,
                                          c3_W1 + 256 * 256, p_w2f3, c3_b2, p_hA);
  // classifier
  gemm_mfma<128, 256, 1, 0><<<NPTS / 32, 256, 0, stream>>>(
      p_hA, p_whW1, h_b1, nullptr, nullptr, p_c1);
  gemm_mfma<128, 128, 1, 0><<<NPTS / 32, 256, 0, stream>>>(
      p_c1, p_whW2, h_b2, nullptr, nullptr, p_c2);
  final_k<<<NPTS, 64, 0, stream>>>(p_c2, h_W3, h_b3, p_sidx, out);

  (void)in_sizes; (void)n_in; (void)out_size; (void)ws_size;
}

// Round 15
// 288.861 us; speedup vs baseline: 1.3000x; 1.3000x over previous
//
#include <hip/hip_runtime.h>
#include <hip/hip_bf16.h>
#include <math.h>

#define NPTS 8192
#define CDIM 256
#define HDIM 128
#define NCH  32
#define CH   (NPTS / NCH)     // 256 candidates per chunk
#define CAP  48               // qualifier buffer slots per target

typedef __attribute__((ext_vector_type(8))) short bf16x8;
typedef __attribute__((ext_vector_type(4))) float f32x4;
typedef unsigned long long u64;

static __device__ __forceinline__ short f2bf(float f) {
  __hip_bfloat16 h = __float2bfloat16(f);
  return *reinterpret_cast<short*>(&h);
}

// median-of-3: one VALU op; med3(lo, key, hi) == min(max(lo,key),hi) for lo<=hi
static __device__ __forceinline__ unsigned umed3(unsigned a, unsigned b,
                                                 unsigned c) {
  unsigned d;
  asm("v_med3_u32 %0, %1, %2, %3" : "=v"(d) : "v"(a), "v"(b), "v"(c));
  return d;
}

// Bit-exact d2 key shared by both kNN passes.
static __device__ __forceinline__ unsigned d2key(float4 p, float4 c) {
  float dot = fmaf(p.x, c.x, fmaf(p.y, c.y, p.z * c.z));
  float d2 = fmaf(-2.0f, dot, p.w + c.w);
  return __float_as_uint(fmaxf(d2, 0.0f));
}

// u32 branchless top-16 insert: b[s] = med3(b[s-1], key, b[s]) (16 indep ops).
#define U32INIT unsigned b0=~0u,b1=~0u,b2=~0u,b3=~0u,b4=~0u,b5=~0u,b6=~0u, \
                         b7=~0u,b8=~0u,b9=~0u,b10=~0u,b11=~0u,b12=~0u, \
                         b13=~0u,b14=~0u,b15=~0u;
#define U32CHAIN(key) { \
  b15 = umed3(b14, key, b15); b14 = umed3(b13, key, b14); \
  b13 = umed3(b12, key, b13); b12 = umed3(b11, key, b12); \
  b11 = umed3(b10, key, b11); b10 = umed3(b9,  key, b10); \
  b9  = umed3(b8,  key, b9);  b8  = umed3(b7,  key, b8);  \
  b7  = umed3(b6,  key, b7);  b6  = umed3(b5,  key, b6);  \
  b5  = umed3(b4,  key, b5);  b4  = umed3(b3,  key, b4);  \
  b3  = umed3(b2,  key, b3);  b2  = umed3(b1,  key, b2);  \
  b1  = umed3(b0,  key, b1);  b0  = min(b0, key); }

// u64 exact (d2,idx) insertion chain for the final select.
#define KSTEP(s) { bool sw_ = key < k##s; u64 t_ = k##s; \
                   k##s = sw_ ? key : t_; key = sw_ ? t_ : key; }
#define KCHAIN KSTEP(0) KSTEP(1) KSTEP(2) KSTEP(3) KSTEP(4) KSTEP(5) \
               KSTEP(6) KSTEP(7) KSTEP(8) KSTEP(9) KSTEP(10) KSTEP(11) \
               KSTEP(12) KSTEP(13) KSTEP(14) KSTEP(15)
#define KINIT u64 k0=~0ULL,k1=~0ULL,k2=~0ULL,k3=~0ULL,k4=~0ULL,k5=~0ULL, \
                  k6=~0ULL,k7=~0ULL,k8=~0ULL,k9=~0ULL,k10=~0ULL,k11=~0ULL, \
                  k12=~0ULL,k13=~0ULL,k14=~0ULL,k15=~0ULL;

// ---------------------------------------------------------------------------
// Fused prep: 7 fragment-major bf16 weight conversions + pos4 + conv1 TU.
// blocks [0,1280): the five 256x256 weights; [1280,1408): h_W1 (256x128);
// [1408,1472): h_W2 (128x128); [1472,1504): pos4; [1504,2016): tu1 (16 rows).
// ---------------------------------------------------------------------------
__global__ __launch_bounds__(256) void prep_all(
    const float* __restrict__ c1W2, const float* __restrict__ c2W2,
    const float* __restrict__ c3W2, const float* __restrict__ c2W1,
    const float* __restrict__ c3W1, const float* __restrict__ hW1,
    const float* __restrict__ hW2,
    short* __restrict__ w2f1, short* __restrict__ w2f2,
    short* __restrict__ w2f3, short* __restrict__ wc2a,
    short* __restrict__ wc3a, short* __restrict__ whW1,
    short* __restrict__ whW2,
    const float* __restrict__ pos, float4* __restrict__ pos4,
    const float* __restrict__ c1W1, const float* __restrict__ c1b1,
    float* __restrict__ TU) {
  int b = blockIdx.x, tid = threadIdx.x;
  if (b < 1280) {                 // 256x256 weights, KS=8
    const float* W; short* wf; int rb;
    if (b < 256)       { W = c1W2; wf = w2f1; rb = b; }
    else if (b < 512)  { W = c2W2; wf = w2f2; rb = b - 256; }
    else if (b < 768)  { W = c3W2; wf = w2f3; rb = b - 512; }
    else if (b < 1024) { W = c2W1; wf = wc2a; rb = b - 768; }
    else               { W = c3W1; wf = wc3a; rb = b - 1024; }
    int t = rb * 256 + tid;
    int q = t & 7, l = (t >> 3) & 63, F = t >> 9;
    int ks = F & 7, c16 = F >> 3;
    int k = ks * 32 + ((l >> 4) << 3) + q;
    int c = c16 * 16 + (l & 15);
    wf[t] = f2bf(W[k * 256 + c]);
  } else if (b < 1408) {          // h_W1: KDIM 256 (KS=8), NCOLS 128
    int t = (b - 1280) * 256 + tid;
    int q = t & 7, l = (t >> 3) & 63, F = t >> 9;
    int ks = F & 7, c16 = F >> 3;
    int k = ks * 32 + ((l >> 4) << 3) + q;
    int c = c16 * 16 + (l & 15);
    whW1[t] = f2bf(hW1[k * 128 + c]);
  } else if (b < 1472) {          // h_W2: KDIM 128 (KS=4), NCOLS 128
    int t = (b - 1408) * 256 + tid;
    int q = t & 7, l = (t >> 3) & 63, F = t >> 9;
    int ks = F & 3, c16 = F >> 2;
    int k = ks * 32 + ((l >> 4) << 3) + q;
    int c = c16 * 16 + (l & 15);
    whW2[t] = f2bf(hW2[k * 128 + c]);
  } else if (b < 1504) {          // pos4
    int i = (b - 1472) * 256 + tid;
    float x = pos[3 * i], y = pos[3 * i + 1], z = pos[3 * i + 2];
    pos4[i] = make_float4(x, y, z, x * x + y * y + z * z);
  } else {                        // conv1 TU: TU[i][c] = b1 + pos.(W1h+W1p)
    int c = tid;
    float w0 = c1W1[c]       + c1W1[768 + c];
    float w1 = c1W1[256 + c] + c1W1[1024 + c];
    float w2 = c1W1[512 + c] + c1W1[1280 + c];
    float bv = c1b1[c];
    int i0 = (b - 1504) * 16;
#pragma unroll
    for (int r = 0; r < 16; ++r) {
      int i = i0 + r;
      float x = pos[3 * i], y = pos[3 * i + 1], z = pos[3 * i + 2];
      TU[(size_t)i * 256 + c] = fmaf(x, w0, fmaf(y, w1, fmaf(z, w2, bv)));
    }
  }
}

// ---------------------------------------------------------------------------
// kNN pass 1: thread = (target i, chunk ch). 16 smallest d2 VALUES (u32),
// 4x unrolled (batched LDS loads + key ILP), written contiguously per (ch,i).
// ---------------------------------------------------------------------------
__global__ __launch_bounds__(256) void knn_d2p1(const float4* __restrict__ pos4,
                                                unsigned* __restrict__ v) {
  __shared__ float4 cand[CH];
  int ch = blockIdx.x & (NCH - 1);
  int i  = (blockIdx.x >> 5) * 256 + threadIdx.x;
  cand[threadIdx.x] = pos4[ch * CH + threadIdx.x];
  __syncthreads();

  float4 p = pos4[i];
  U32INIT
  for (int jj = 0; jj < CH; jj += 4) {
    float4 c0 = cand[jj], c1 = cand[jj + 1], c2 = cand[jj + 2],
           c3 = cand[jj + 3];
    unsigned x0 = d2key(p, c0), x1 = d2key(p, c1);
    unsigned x2 = d2key(p, c2), x3 = d2key(p, c3);
    U32CHAIN(x0) U32CHAIN(x1) U32CHAIN(x2) U32CHAIN(x3)
  }
  uint4* dst = reinterpret_cast<uint4*>(v + ((size_t)ch * NPTS + i) * 16);
  dst[0] = make_uint4(b0, b1, b2, b3);
  dst[1] = make_uint4(b4, b5, b6, b7);
  dst[2] = make_uint4(b8, b9, b10, b11);
  dst[3] = make_uint4(b12, b13, b14, b15);
}

// ---------------------------------------------------------------------------
// kNN merge: one WAVE per target; 16 selection rounds over 32 sorted 16-lists
// (lane = half-chunk, 8 values). The advance step is a STATIC register shift
// (h=r1, r1=r2, ...) predicated on lane==src_lane -- all register accesses
// compile-time constant, no scratch spill (rule #20). Exact 16th -> T[i].
// ---------------------------------------------------------------------------
__global__ __launch_bounds__(256) void knn_merge(const unsigned* __restrict__ v,
                                                 unsigned* __restrict__ T,
                                                 unsigned* __restrict__ cnt) {
  int wv = threadIdx.x >> 6, lane = threadIdx.x & 63;
  int i = blockIdx.x * 4 + wv;
  int ch = lane >> 1, half = lane & 1;
  const uint4* src = reinterpret_cast<const uint4*>(
      v + ((size_t)ch * NPTS + i) * 16 + half * 8);
  uint4 a = src[0], b = src[1];
  unsigned r1 = a.y, r2 = a.z, r3 = a.w;
  unsigned r4 = b.x, r5 = b.y, r6 = b.z, r7 = b.w;
  unsigned h = a.x;
  unsigned wmin = 0;
#pragma unroll
  for (int round = 0; round < 16; ++round) {
    unsigned m = h;
    m = min(m, (unsigned)__shfl_xor((int)m, 1));
    m = min(m, (unsigned)__shfl_xor((int)m, 2));
    m = min(m, (unsigned)__shfl_xor((int)m, 4));
    m = min(m, (unsigned)__shfl_xor((int)m, 8));
    m = min(m, (unsigned)__shfl_xor((int)m, 16));
    m = min(m, (unsigned)__shfl_xor((int)m, 32));
    wmin = m;
    u64 ball = __ballot(h == m);
    bool adv = (lane == __ffsll(ball) - 1);
    h  = adv ? r1 : h;
    r1 = adv ? r2 : r1;
    r2 = adv ? r3 : r2;
    r3 = adv ? r4 : r3;
    r4 = adv ? r5 : r4;
    r5 = adv ? r6 : r5;
    r6 = adv ? r7 : r6;
    r7 = adv ? 0xFFFFFFFFu : r7;
  }
  if (lane == 0) { T[i] = wmin; cnt[i] = 0; }
}

// ---------------------------------------------------------------------------
// kNN pass 2: 8x-unrolled re-scan (identical d2key bits); min8 guard, then
// rare qualifier path (d2 <= T) appends to the CAP-slot buffer.
// ---------------------------------------------------------------------------
__global__ __launch_bounds__(256) void knn_d2p2(const float4* __restrict__ pos4,
                                                const unsigned* __restrict__ T,
                                                unsigned* __restrict__ cnt,
                                                u64* __restrict__ cbuf) {
  __shared__ float4 cand[CH];
  int ch = blockIdx.x & (NCH - 1);
  int i  = (blockIdx.x >> 5) * 256 + threadIdx.x;
  cand[threadIdx.x] = pos4[ch * CH + threadIdx.x];
  __syncthreads();

  float4 p = pos4[i];
  unsigned Ti = T[i];
  int jb = ch * CH;
  for (int jj = 0; jj < CH; jj += 8) {
    unsigned k[8];
#pragma unroll
    for (int u = 0; u < 8; ++u) k[u] = d2key(p, cand[jj + u]);
    unsigned m = min(min(min(k[0], k[1]), min(k[2], k[3])),
                     min(min(k[4], k[5]), min(k[6], k[7])));
    if (m <= Ti) {
#pragma unroll
      for (int u = 0; u < 8; ++u) {
        if (k[u] <= Ti) {
          unsigned slot = atomicAdd(&cnt[i], 1u);
          if (slot < CAP)
            cbuf[(size_t)i * CAP + slot] =
                ((u64)k[u] << 32) | (unsigned)(jb + jj + u);
        }
      }
    }
  }
}

// ---------------------------------------------------------------------------
// kNN select: exact lexicographic (d2, idx) top-16 over the <=CAP qualifiers.
// ---------------------------------------------------------------------------
__global__ __launch_bounds__(256) void knn_select(const unsigned* __restrict__ cnt,
                                                  const u64* __restrict__ cbuf,
                                                  int* __restrict__ idx_out) {
  int i = blockIdx.x * 256 + threadIdx.x;
  int c = (int)min(cnt[i], (unsigned)CAP);
  KINIT
#pragma unroll 1
  for (int q = 0; q < c; ++q) {
    u64 key = cbuf[(size_t)i * CAP + q];
    if (key < k15) { KCHAIN }
  }
  int* o = idx_out + i * 16;
  o[0]=(int)(unsigned)k0;   o[1]=(int)(unsigned)k1;   o[2]=(int)(unsigned)k2;
  o[3]=(int)(unsigned)k3;   o[4]=(int)(unsigned)k4;   o[5]=(int)(unsigned)k5;
  o[6]=(int)(unsigned)k6;   o[7]=(int)(unsigned)k7;   o[8]=(int)(unsigned)k8;
  o[9]=(int)(unsigned)k9;   o[10]=(int)(unsigned)k10; o[11]=(int)(unsigned)k11;
  o[12]=(int)(unsigned)k12; o[13]=(int)(unsigned)k13; o[14]=(int)(unsigned)k14;
  o[15]=(int)(unsigned)k15;
}

// ---------------------------------------------------------------------------
// MFMA GEMM: out[M][NCOLS] = act(bf16(A[M][KDIM]) @ Wf + bias [+ pos@W1p]).
// ---------------------------------------------------------------------------
template <int NCOLS, int KDIM, int ACT, int ADDP>
__global__ __launch_bounds__(256) void gemm_mfma(
    const float* __restrict__ A,
    const short* __restrict__ wf,
    const float* __restrict__ bias,
    const float* __restrict__ pos,
    const float* __restrict__ W1p,
    float* __restrict__ out) {
  constexpr int KS = KDIM / 32;
  constexpr int NF = NCOLS / 64;
  __shared__ __align__(16) short As[32 * KDIM];

  int tid = threadIdx.x;
  int row0 = blockIdx.x * 32;

  {  // stage A: 32 rows x KDIM fp32 -> bf16, swizzled
    int row = tid & 31, wq = tid >> 5;
    const float* Ar = A + (size_t)(row0 + row) * KDIM;
#pragma unroll
    for (int q = 0; q < KDIM / 64; ++q) {
      int c0 = wq * 8 + q * 64;
      float4 a = *reinterpret_cast<const float4*>(Ar + c0);
      float4 b = *reinterpret_cast<const float4*>(Ar + c0 + 4);
      bf16x8 o;
      o[0] = f2bf(a.x); o[1] = f2bf(a.y); o[2] = f2bf(a.z); o[3] = f2bf(a.w);
      o[4] = f2bf(b.x); o[5] = f2bf(b.y); o[6] = f2bf(b.z); o[7] = f2bf(b.w);
      int byte = row * (KDIM * 2) + c0 * 2;
      byte ^= (row & 7) << 4;
      *reinterpret_cast<bf16x8*>(reinterpret_cast<char*>(As) + byte) = o;
    }
  }
  __syncthreads();

  int l = tid & 63, w = tid >> 6;
  int lhi = l >> 4, llo = l & 15;
  f32x4 zero = {0.f, 0.f, 0.f, 0.f};
  f32x4 acc[2][NF];
#pragma unroll
  for (int m = 0; m < 2; ++m)
#pragma unroll
    for (int n = 0; n < NF; ++n) acc[m][n] = zero;

  const bf16x8* WfV = reinterpret_cast<const bf16x8*>(wf);
#pragma unroll
  for (int ks = 0; ks < KS; ++ks) {
    bf16x8 af[2], bfr[NF];
#pragma unroll
    for (int m = 0; m < 2; ++m) {
      int r = m * 16 + llo;
      int byte = r * (KDIM * 2) + ks * 64 + lhi * 16;
      byte ^= (r & 7) << 4;
      af[m] = *reinterpret_cast<const bf16x8*>(
          reinterpret_cast<const char*>(As) + byte);
    }
#pragma unroll
    for (int n = 0; n < NF; ++n)
      bfr[n] = WfV[((w * NF + n) * KS + ks) * 64 + l];
#pragma unroll
    for (int m = 0; m < 2; ++m)
#pragma unroll
      for (int n = 0; n < NF; ++n)
        acc[m][n] = __builtin_amdgcn_mfma_f32_16x16x32_bf16(af[m], bfr[n],
                                                            acc[m][n], 0, 0, 0);
  }

  int cc[NF];
  float bv[NF], u0[NF], u1[NF], u2[NF];
#pragma unroll
  for (int n = 0; n < NF; ++n) {
    cc[n] = (w * NF + n) * 16 + llo;
    bv[n] = bias[cc[n]];
    if constexpr (ADDP) {
      u0[n] = W1p[cc[n]];
      u1[n] = W1p[NCOLS + cc[n]];
      u2[n] = W1p[2 * NCOLS + cc[n]];
    } else { u0[n] = u1[n] = u2[n] = 0.f; }
  }
#pragma unroll
  for (int m = 0; m < 2; ++m)
#pragma unroll
    for (int j = 0; j < 4; ++j) {
      int r = row0 + m * 16 + lhi * 4 + j;
      float px = 0.f, py = 0.f, pz = 0.f;
      if constexpr (ADDP) { px = pos[3*r]; py = pos[3*r+1]; pz = pos[3*r+2]; }
#pragma unroll
      for (int n = 0; n < NF; ++n) {
        float v = acc[m][n][j] + bv[n];
        if constexpr (ADDP) v += px * u0[n] + py * u1[n] + pz * u2[n];
        if (ACT == 1) v = fmaxf(v, 0.0f);
        out[(size_t)r * NCOLS + cc[n]] = v;
      }
    }
}

// ---------------------------------------------------------------------------
// MFMA conv: block = 4 targets (64 rows = 4 x 16 nbrs) x 256 cols, K=256.
// ---------------------------------------------------------------------------
__global__ __launch_bounds__(256) void conv_mfma(
    const float* __restrict__ TU,
    const float* __restrict__ pos,
    const int* __restrict__ idx,
    const float* __restrict__ W1p,
    const short* __restrict__ w2f,
    const float* __restrict__ b2,
    float* __restrict__ hout) {
  __shared__ __align__(16) short m1s[64 * 256];
  __shared__ float Ub[4][256];
  __shared__ int js[64];

  int tid = threadIdx.x;
  int t0 = blockIdx.x * 4;
  if (tid < 64) js[tid] = idx[(t0 + (tid >> 4)) * 16 + (tid & 15)];
#pragma unroll
  for (int q = 0; q < 4; ++q) {
    int e = tid + 256 * q;
    int tg = e >> 8, c = e & 255;
    float x = pos[3 * (t0 + tg)], y = pos[3 * (t0 + tg) + 1],
          z = pos[3 * (t0 + tg) + 2];
    Ub[tg][c] = x * W1p[c] + y * W1p[256 + c] + z * W1p[512 + c];
  }
  __syncthreads();

  {
    int row = tid & 63;
    int wq = tid >> 6;
    int jrow = js[row];
    const float* TUj = TU + (size_t)jrow * 256;
    const float* Ui = &Ub[row >> 4][0];
#pragma unroll
    for (int q = 0; q < 8; ++q) {
      int c0 = wq * 8 + q * 32;
      float4 a = *reinterpret_cast<const float4*>(TUj + c0);
      float4 b = *reinterpret_cast<const float4*>(TUj + c0 + 4);
      float4 ua = *reinterpret_cast<const float4*>(Ui + c0);
      float4 ub = *reinterpret_cast<const float4*>(Ui + c0 + 4);
      bf16x8 o;
      o[0] = f2bf(fmaxf(a.x - ua.x, 0.f));
      o[1] = f2bf(fmaxf(a.y - ua.y, 0.f));
      o[2] = f2bf(fmaxf(a.z - ua.z, 0.f));
      o[3] = f2bf(fmaxf(a.w - ua.w, 0.f));
      o[4] = f2bf(fmaxf(b.x - ub.x, 0.f));
      o[5] = f2bf(fmaxf(b.y - ub.y, 0.f));
      o[6] = f2bf(fmaxf(b.z - ub.z, 0.f));
      o[7] = f2bf(fmaxf(b.w - ub.w, 0.f));
      int byte = row * 512 + c0 * 2;
      byte ^= (row & 7) << 4;
      *reinterpret_cast<bf16x8*>(reinterpret_cast<char*>(m1s) + byte) = o;
    }
  }
  __syncthreads();

  int l = tid & 63, w = tid >> 6;
  int lhi = l >> 4, llo = l & 15;
  f32x4 zero = {0.f, 0.f, 0.f, 0.f};
  f32x4 acc[4][4];
#pragma unroll
  for (int m = 0; m < 4; ++m)
#pragma unroll
    for (int n = 0; n < 4; ++n) acc[m][n] = zero;

  const bf16x8* Wf = reinterpret_cast<const bf16x8*>(w2f);
#pragma unroll
  for (int ks = 0; ks < 8; ++ks) {
    int k0 = ks * 32;
    bf16x8 af[4], bfr[4];
#pragma unroll
    for (int m = 0; m < 4; ++m) {
      int r = m * 16 + llo;
      int byte = r * 512 + k0 * 2 + lhi * 16;
      byte ^= (r & 7) << 4;
      af[m] = *reinterpret_cast<const bf16x8*>(
          reinterpret_cast<const char*>(m1s) + byte);
    }
#pragma unroll
    for (int n = 0; n < 4; ++n)
      bfr[n] = Wf[((w * 4 + n) * 8 + ks) * 64 + l];
#pragma unroll
    for (int m = 0; m < 4; ++m)
#pragma unroll
      for (int n = 0; n < 4; ++n)
        acc[m][n] = __builtin_amdgcn_mfma_f32_16x16x32_bf16(af[m], bfr[n],
                                                            acc[m][n], 0, 0, 0);
  }

#pragma unroll
  for (int m = 0; m < 4; ++m)
#pragma unroll
    for (int n = 0; n < 4; ++n) {
      float v = fmaxf(fmaxf(acc[m][n][0], acc[m][n][1]),
                      fmaxf(acc[m][n][2], acc[m][n][3]));
      v = fmaxf(v, __shfl_xor(v, 16));
      v = fmaxf(v, __shfl_xor(v, 32));
      if (lhi == 0) {
        int c = w * 64 + n * 16 + llo;
        hout[(size_t)(t0 + m) * CDIM + c] = fmaxf(v + b2[c], 0.0f);
      }
    }
}

// ---------------------------------------------------------------------------
// Final layer: out[r] = sigmoid(h2[r] . w3 + b3); one wave per row.
// ---------------------------------------------------------------------------
__global__ __launch_bounds__(64) void final_k(const float* __restrict__ h2,
                                              const float* __restrict__ w3,
                                              const float* __restrict__ b3,
                                              float* __restrict__ out) {
  int r = blockIdx.x, l = threadIdx.x;
  float s = h2[(size_t)r * HDIM + l] * w3[l] +
            h2[(size_t)r * HDIM + 64 + l] * w3[64 + l];
#pragma unroll
  for (int o = 32; o > 0; o >>= 1) s += __shfl_down(s, o);
  if (l == 0) out[r] = 1.0f / (1.0f + expf(-(s + b3[0])));
}

extern "C" void kernel_launch(void* const* d_in, const int* in_sizes, int n_in,
                              void* d_out, int out_size, void* d_ws,
                              size_t ws_size, hipStream_t stream) {
  const float* pos   = (const float*)d_in[0];
  const float* c1_W1 = (const float*)d_in[1];
  const float* c1_b1 = (const float*)d_in[2];
  const float* c1_W2 = (const float*)d_in[3];
  const float* c1_b2 = (const float*)d_in[4];
  const float* c2_W1 = (const float*)d_in[5];
  const float* c2_b1 = (const float*)d_in[6];
  const float* c2_W2 = (const float*)d_in[7];
  const float* c2_b2 = (const float*)d_in[8];
  const float* c3_W1 = (const float*)d_in[9];
  const float* c3_b1 = (const float*)d_in[10];
  const float* c3_W2 = (const float*)d_in[11];
  const float* c3_b2 = (const float*)d_in[12];
  const float* h_W1  = (const float*)d_in[13];
  const float* h_b1  = (const float*)d_in[14];
  const float* h_W2  = (const float*)d_in[15];
  const float* h_b2  = (const float*)d_in[16];
  const float* h_W3  = (const float*)d_in[17];
  const float* h_b3  = (const float*)d_in[18];
  float* out = (float*)d_out;

  char* w = (char*)d_ws;
  const size_t MB = 1 << 20;
  const size_t KB = 1 << 10;
  int*      p_idx  = (int*)w;                           // 512K
  float4*   p_pos4 = (float4*)(w + 512 * KB);           // 128K
  unsigned* p_T    = (unsigned*)(w + 640 * KB);         // 32K
  unsigned* p_cnt  = (unsigned*)(w + 672 * KB);         // 32K
  short*    p_w2f1 = (short*)(w + 704 * KB);            // 128K
  short*    p_w2f2 = (short*)(w + 832 * KB);            // 128K
  short*    p_w2f3 = (short*)(w + 960 * KB);            // 128K
  short*    p_wc2a = (short*)(w + 1088 * KB);           // 128K
  short*    p_wc3a = (short*)(w + 1216 * KB);           // 128K
  short*    p_whW1 = (short*)(w + 1344 * KB);           // 64K
  short*    p_whW2 = (short*)(w + 1408 * KB);           // 32K
  u64*      p_cbuf = (u64*)(w + 1536 * KB);             // 3MB
  float*    p_TU   = (float*)(w + 5 * MB);              // 8MB  [5,13)
  unsigned* p_v    = (unsigned*)(w + 13 * MB);          // 16MB [13,29) knn only
  float*    p_hA   = (float*)(w + 13 * MB);             // 8MB  (v dead)
  float*    p_hB   = (float*)(w + 21 * MB);             // 8MB  (v dead)
  float*    p_c1   = (float*)(w + 5 * MB);              // 4MB  (TU dead)
  float*    p_c2   = (float*)(w + 9 * MB);              // 4MB

  // fused prep: weights, pos4, conv1 TU (TU region untouched by kNN)
  prep_all<<<2016, 256, 0, stream>>>(
      c1_W2, c2_W2, c3_W2, c2_W1, c3_W1, h_W1, h_W2,
      p_w2f1, p_w2f2, p_w2f3, p_wc2a, p_wc3a, p_whW1, p_whW2,
      pos, p_pos4, c1_W1, c1_b1, p_TU);

  // kNN: two-pass exact top-16 (wave-parallel merge, static-shift advance)
  knn_d2p1<<<(NPTS / 256) * NCH, 256, 0, stream>>>(p_pos4, p_v);
  knn_merge<<<NPTS / 4, 256, 0, stream>>>(p_v, p_T, p_cnt);
  knn_d2p2<<<(NPTS / 256) * NCH, 256, 0, stream>>>(p_pos4, p_T, p_cnt, p_cbuf);
  knn_select<<<NPTS / 256, 256, 0, stream>>>(p_cnt, p_cbuf, p_idx);

  // conv1
  conv_mfma<<<NPTS / 4, 256, 0, stream>>>(p_TU, pos, p_idx, c1_W1 + 3 * 256,
                                          p_w2f1, c1_b2, p_hA);
  // conv2
  gemm_mfma<256, 256, 0, 1><<<NPTS / 32, 256, 0, stream>>>(
      p_hA, p_wc2a, c2_b1, pos, c2_W1 + 256 * 256, p_TU);
  conv_mfma<<<NPTS / 4, 256, 0, stream>>>(p_TU, pos, p_idx, c2_W1 + 256 * 256,
                                          p_w2f2, c2_b2, p_hB);
  // conv3
  gemm_mfma<256, 256, 0, 1><<<NPTS / 32, 256, 0, stream>>>(
      p_hB, p_wc3a, c3_b1, pos, c3_W1 + 256 * 256, p_TU);
  conv_mfma<<<NPTS / 4, 256, 0, stream>>>(p_TU, pos, p_idx, c3_W1 + 256 * 256,
                                          p_w2f3, c3_b2, p_hA);
  // classifier
  gemm_mfma<128, 256, 1, 0><<<NPTS / 32, 256, 0, stream>>>(
      p_hA, p_whW1, h_b1, nullptr, nullptr, p_c1);
  gemm_mfma<128, 128, 1, 0><<<NPTS / 32, 256, 0, stream>>>(
      p_c1, p_whW2, h_b2, nullptr, nullptr, p_c2);
  final_k<<<NPTS, 64, 0, stream>>>(p_c2, h_W3, h_b3, out);

  (void)in_sizes; (void)n_in; (void)out_size; (void)ws_size;
}

// Round 16
// 253.418 us; speedup vs baseline: 1.4818x; 1.1399x over previous
//
#include <hip/hip_runtime.h>
#include <hip/hip_bf16.h>
#include <math.h>

#define NPTS 8192
#define CDIM 256
#define HDIM 128
#define NCH  32
#define CH   (NPTS / NCH)     // 256 candidates per chunk
#define CAP  48               // qualifier buffer slots per target

typedef __attribute__((ext_vector_type(8))) short bf16x8;
typedef __attribute__((ext_vector_type(4))) float f32x4;
typedef unsigned long long u64;

static __device__ __forceinline__ short f2bf(float f) {
  __hip_bfloat16 h = __float2bfloat16(f);
  return *reinterpret_cast<short*>(&h);
}
static __device__ __forceinline__ float bf2f(short s) {
  return __uint_as_float(((unsigned)(unsigned short)s) << 16);
}

// median-of-3: one VALU op; med3(lo, key, hi) == min(max(lo,key),hi) for lo<=hi
static __device__ __forceinline__ unsigned umed3(unsigned a, unsigned b,
                                                 unsigned c) {
  unsigned d;
  asm("v_med3_u32 %0, %1, %2, %3" : "=v"(d) : "v"(a), "v"(b), "v"(c));
  return d;
}

// Bit-exact d2 key shared by both kNN passes.
static __device__ __forceinline__ unsigned d2key(float4 p, float4 c) {
  float dot = fmaf(p.x, c.x, fmaf(p.y, c.y, p.z * c.z));
  float d2 = fmaf(-2.0f, dot, p.w + c.w);
  return __float_as_uint(fmaxf(d2, 0.0f));
}

#define U32INIT unsigned b0=~0u,b1=~0u,b2=~0u,b3=~0u,b4=~0u,b5=~0u,b6=~0u, \
                         b7=~0u,b8=~0u,b9=~0u,b10=~0u,b11=~0u,b12=~0u, \
                         b13=~0u,b14=~0u,b15=~0u;
#define U32CHAIN(key) { \
  b15 = umed3(b14, key, b15); b14 = umed3(b13, key, b14); \
  b13 = umed3(b12, key, b13); b12 = umed3(b11, key, b12); \
  b11 = umed3(b10, key, b11); b10 = umed3(b9,  key, b10); \
  b9  = umed3(b8,  key, b9);  b8  = umed3(b7,  key, b8);  \
  b7  = umed3(b6,  key, b7);  b6  = umed3(b5,  key, b6);  \
  b5  = umed3(b4,  key, b5);  b4  = umed3(b3,  key, b4);  \
  b3  = umed3(b2,  key, b3);  b2  = umed3(b1,  key, b2);  \
  b1  = umed3(b0,  key, b1);  b0  = min(b0, key); }

#define KSTEP(s) { bool sw_ = key < k##s; u64 t_ = k##s; \
                   k##s = sw_ ? key : t_; key = sw_ ? t_ : key; }
#define KCHAIN KSTEP(0) KSTEP(1) KSTEP(2) KSTEP(3) KSTEP(4) KSTEP(5) \
               KSTEP(6) KSTEP(7) KSTEP(8) KSTEP(9) KSTEP(10) KSTEP(11) \
               KSTEP(12) KSTEP(13) KSTEP(14) KSTEP(15)
#define KINIT u64 k0=~0ULL,k1=~0ULL,k2=~0ULL,k3=~0ULL,k4=~0ULL,k5=~0ULL, \
                  k6=~0ULL,k7=~0ULL,k8=~0ULL,k9=~0ULL,k10=~0ULL,k11=~0ULL, \
                  k12=~0ULL,k13=~0ULL,k14=~0ULL,k15=~0ULL;

// ---------------------------------------------------------------------------
// Fused prep: 7 fragment-major bf16 weight conversions + pos4 + conv1 TU
// (TU stored bf16).
// ---------------------------------------------------------------------------
__global__ __launch_bounds__(256) void prep_all(
    const float* __restrict__ c1W2, const float* __restrict__ c2W2,
    const float* __restrict__ c3W2, const float* __restrict__ c2W1,
    const float* __restrict__ c3W1, const float* __restrict__ hW1,
    const float* __restrict__ hW2,
    short* __restrict__ w2f1, short* __restrict__ w2f2,
    short* __restrict__ w2f3, short* __restrict__ wc2a,
    short* __restrict__ wc3a, short* __restrict__ whW1,
    short* __restrict__ whW2,
    const float* __restrict__ pos, float4* __restrict__ pos4,
    const float* __restrict__ c1W1, const float* __restrict__ c1b1,
    short* __restrict__ TU) {
  int b = blockIdx.x, tid = threadIdx.x;
  if (b < 1280) {                 // 256x256 weights, KS=8
    const float* W; short* wf; int rb;
    if (b < 256)       { W = c1W2; wf = w2f1; rb = b; }
    else if (b < 512)  { W = c2W2; wf = w2f2; rb = b - 256; }
    else if (b < 768)  { W = c3W2; wf = w2f3; rb = b - 512; }
    else if (b < 1024) { W = c2W1; wf = wc2a; rb = b - 768; }
    else               { W = c3W1; wf = wc3a; rb = b - 1024; }
    int t = rb * 256 + tid;
    int q = t & 7, l = (t >> 3) & 63, F = t >> 9;
    int ks = F & 7, c16 = F >> 3;
    int k = ks * 32 + ((l >> 4) << 3) + q;
    int c = c16 * 16 + (l & 15);
    wf[t] = f2bf(W[k * 256 + c]);
  } else if (b < 1408) {          // h_W1: KDIM 256 (KS=8), NCOLS 128
    int t = (b - 1280) * 256 + tid;
    int q = t & 7, l = (t >> 3) & 63, F = t >> 9;
    int ks = F & 7, c16 = F >> 3;
    int k = ks * 32 + ((l >> 4) << 3) + q;
    int c = c16 * 16 + (l & 15);
    whW1[t] = f2bf(hW1[k * 128 + c]);
  } else if (b < 1472) {          // h_W2: KDIM 128 (KS=4), NCOLS 128
    int t = (b - 1408) * 256 + tid;
    int q = t & 7, l = (t >> 3) & 63, F = t >> 9;
    int ks = F & 3, c16 = F >> 2;
    int k = ks * 32 + ((l >> 4) << 3) + q;
    int c = c16 * 16 + (l & 15);
    whW2[t] = f2bf(hW2[k * 128 + c]);
  } else if (b < 1504) {          // pos4
    int i = (b - 1472) * 256 + tid;
    float x = pos[3 * i], y = pos[3 * i + 1], z = pos[3 * i + 2];
    pos4[i] = make_float4(x, y, z, x * x + y * y + z * z);
  } else {                        // conv1 TU (bf16): b1 + pos.(W1h+W1p)
    int c = tid;
    float w0 = c1W1[c]       + c1W1[768 + c];
    float w1 = c1W1[256 + c] + c1W1[1024 + c];
    float w2 = c1W1[512 + c] + c1W1[1280 + c];
    float bv = c1b1[c];
    int i0 = (b - 1504) * 16;
#pragma unroll
    for (int r = 0; r < 16; ++r) {
      int i = i0 + r;
      float x = pos[3 * i], y = pos[3 * i + 1], z = pos[3 * i + 2];
      TU[(size_t)i * 256 + c] = f2bf(fmaf(x, w0, fmaf(y, w1, fmaf(z, w2, bv))));
    }
  }
}

// ---------------------------------------------------------------------------
// kNN pass 1: thread = (target i, chunk ch). 16 smallest d2 VALUES (u32).
// ---------------------------------------------------------------------------
__global__ __launch_bounds__(256) void knn_d2p1(const float4* __restrict__ pos4,
                                                unsigned* __restrict__ v) {
  __shared__ float4 cand[CH];
  int ch = blockIdx.x & (NCH - 1);
  int i  = (blockIdx.x >> 5) * 256 + threadIdx.x;
  cand[threadIdx.x] = pos4[ch * CH + threadIdx.x];
  __syncthreads();

  float4 p = pos4[i];
  U32INIT
  for (int jj = 0; jj < CH; jj += 4) {
    float4 c0 = cand[jj], c1 = cand[jj + 1], c2 = cand[jj + 2],
           c3 = cand[jj + 3];
    unsigned x0 = d2key(p, c0), x1 = d2key(p, c1);
    unsigned x2 = d2key(p, c2), x3 = d2key(p, c3);
    U32CHAIN(x0) U32CHAIN(x1) U32CHAIN(x2) U32CHAIN(x3)
  }
  uint4* dst = reinterpret_cast<uint4*>(v + ((size_t)ch * NPTS + i) * 16);
  dst[0] = make_uint4(b0, b1, b2, b3);
  dst[1] = make_uint4(b4, b5, b6, b7);
  dst[2] = make_uint4(b8, b9, b10, b11);
  dst[3] = make_uint4(b12, b13, b14, b15);
}

// ---------------------------------------------------------------------------
// kNN merge: one WAVE per target; 16 selection rounds, static register-shift
// advance (rule #20 safe). Exact global 16th -> T[i].
// ---------------------------------------------------------------------------
__global__ __launch_bounds__(256) void knn_merge(const unsigned* __restrict__ v,
                                                 unsigned* __restrict__ T,
                                                 unsigned* __restrict__ cnt) {
  int wv = threadIdx.x >> 6, lane = threadIdx.x & 63;
  int i = blockIdx.x * 4 + wv;
  int ch = lane >> 1, half = lane & 1;
  const uint4* src = reinterpret_cast<const uint4*>(
      v + ((size_t)ch * NPTS + i) * 16 + half * 8);
  uint4 a = src[0], b = src[1];
  unsigned r1 = a.y, r2 = a.z, r3 = a.w;
  unsigned r4 = b.x, r5 = b.y, r6 = b.z, r7 = b.w;
  unsigned h = a.x;
  unsigned wmin = 0;
#pragma unroll
  for (int round = 0; round < 16; ++round) {
    unsigned m = h;
    m = min(m, (unsigned)__shfl_xor((int)m, 1));
    m = min(m, (unsigned)__shfl_xor((int)m, 2));
    m = min(m, (unsigned)__shfl_xor((int)m, 4));
    m = min(m, (unsigned)__shfl_xor((int)m, 8));
    m = min(m, (unsigned)__shfl_xor((int)m, 16));
    m = min(m, (unsigned)__shfl_xor((int)m, 32));
    wmin = m;
    u64 ball = __ballot(h == m);
    bool adv = (lane == __ffsll(ball) - 1);
    h  = adv ? r1 : h;
    r1 = adv ? r2 : r1;
    r2 = adv ? r3 : r2;
    r3 = adv ? r4 : r3;
    r4 = adv ? r5 : r4;
    r5 = adv ? r6 : r5;
    r6 = adv ? r7 : r6;
    r7 = adv ? 0xFFFFFFFFu : r7;
  }
  if (lane == 0) { T[i] = wmin; cnt[i] = 0; }
}

// ---------------------------------------------------------------------------
// kNN pass 2: 8x-unrolled re-scan; min8 guard, rare qualifier append.
// ---------------------------------------------------------------------------
__global__ __launch_bounds__(256) void knn_d2p2(const float4* __restrict__ pos4,
                                                const unsigned* __restrict__ T,
                                                unsigned* __restrict__ cnt,
                                                u64* __restrict__ cbuf) {
  __shared__ float4 cand[CH];
  int ch = blockIdx.x & (NCH - 1);
  int i  = (blockIdx.x >> 5) * 256 + threadIdx.x;
  cand[threadIdx.x] = pos4[ch * CH + threadIdx.x];
  __syncthreads();

  float4 p = pos4[i];
  unsigned Ti = T[i];
  int jb = ch * CH;
  for (int jj = 0; jj < CH; jj += 8) {
    unsigned k[8];
#pragma unroll
    for (int u = 0; u < 8; ++u) k[u] = d2key(p, cand[jj + u]);
    unsigned m = min(min(min(k[0], k[1]), min(k[2], k[3])),
                     min(min(k[4], k[5]), min(k[6], k[7])));
    if (m <= Ti) {
#pragma unroll
      for (int u = 0; u < 8; ++u) {
        if (k[u] <= Ti) {
          unsigned slot = atomicAdd(&cnt[i], 1u);
          if (slot < CAP)
            cbuf[(size_t)i * CAP + slot] =
                ((u64)k[u] << 32) | (unsigned)(jb + jj + u);
        }
      }
    }
  }
}

// ---------------------------------------------------------------------------
// kNN select: exact lexicographic (d2, idx) top-16 over the <=CAP qualifiers.
// ---------------------------------------------------------------------------
__global__ __launch_bounds__(256) void knn_select(const unsigned* __restrict__ cnt,
                                                  const u64* __restrict__ cbuf,
                                                  int* __restrict__ idx_out) {
  int i = blockIdx.x * 256 + threadIdx.x;
  int c = (int)min(cnt[i], (unsigned)CAP);
  KINIT
#pragma unroll 1
  for (int q = 0; q < c; ++q) {
    u64 key = cbuf[(size_t)i * CAP + q];
    if (key < k15) { KCHAIN }
  }
  int* o = idx_out + i * 16;
  o[0]=(int)(unsigned)k0;   o[1]=(int)(unsigned)k1;   o[2]=(int)(unsigned)k2;
  o[3]=(int)(unsigned)k3;   o[4]=(int)(unsigned)k4;   o[5]=(int)(unsigned)k5;
  o[6]=(int)(unsigned)k6;   o[7]=(int)(unsigned)k7;   o[8]=(int)(unsigned)k8;
  o[9]=(int)(unsigned)k9;   o[10]=(int)(unsigned)k10; o[11]=(int)(unsigned)k11;
  o[12]=(int)(unsigned)k12; o[13]=(int)(unsigned)k13; o[14]=(int)(unsigned)k14;
  o[15]=(int)(unsigned)k15;
}

// ---------------------------------------------------------------------------
// MFMA GEMM: out = act(A_bf16 @ Wf + bias [+ pos@W1p]).
// A is bf16 -> staging is a pure swizzled copy. OUTBF selects bf16/f32 out.
// ---------------------------------------------------------------------------
template <int NCOLS, int KDIM, int ACT, int ADDP, int OUTBF>
__global__ __launch_bounds__(256) void gemm_mfma(
    const short* __restrict__ A,
    const short* __restrict__ wf,
    const float* __restrict__ bias,
    const float* __restrict__ pos,
    const float* __restrict__ W1p,
    void* __restrict__ outp) {
  constexpr int KS = KDIM / 32;
  constexpr int NF = NCOLS / 64;
  __shared__ __align__(16) short As[32 * KDIM];

  int tid = threadIdx.x;
  int row0 = blockIdx.x * 32;

  {  // stage A: 32 rows x KDIM bf16 -> swizzled LDS (pure copy)
    int row = tid & 31, wq = tid >> 5;
    const short* Ar = A + (size_t)(row0 + row) * KDIM;
#pragma unroll
    for (int q = 0; q < KDIM / 64; ++q) {
      int c0 = wq * 8 + q * 64;
      bf16x8 o = *reinterpret_cast<const bf16x8*>(Ar + c0);
      int byte = row * (KDIM * 2) + c0 * 2;
      byte ^= (row & 7) << 4;
      *reinterpret_cast<bf16x8*>(reinterpret_cast<char*>(As) + byte) = o;
    }
  }
  __syncthreads();

  int l = tid & 63, w = tid >> 6;
  int lhi = l >> 4, llo = l & 15;
  f32x4 zero = {0.f, 0.f, 0.f, 0.f};
  f32x4 acc[2][NF];
#pragma unroll
  for (int m = 0; m < 2; ++m)
#pragma unroll
    for (int n = 0; n < NF; ++n) acc[m][n] = zero;

  const bf16x8* WfV = reinterpret_cast<const bf16x8*>(wf);
#pragma unroll
  for (int ks = 0; ks < KS; ++ks) {
    bf16x8 af[2], bfr[NF];
#pragma unroll
    for (int m = 0; m < 2; ++m) {
      int r = m * 16 + llo;
      int byte = r * (KDIM * 2) + ks * 64 + lhi * 16;
      byte ^= (r & 7) << 4;
      af[m] = *reinterpret_cast<const bf16x8*>(
          reinterpret_cast<const char*>(As) + byte);
    }
#pragma unroll
    for (int n = 0; n < NF; ++n)
      bfr[n] = WfV[((w * NF + n) * KS + ks) * 64 + l];
#pragma unroll
    for (int m = 0; m < 2; ++m)
#pragma unroll
      for (int n = 0; n < NF; ++n)
        acc[m][n] = __builtin_amdgcn_mfma_f32_16x16x32_bf16(af[m], bfr[n],
                                                            acc[m][n], 0, 0, 0);
  }

  int cc[NF];
  float bv[NF], u0[NF], u1[NF], u2[NF];
#pragma unroll
  for (int n = 0; n < NF; ++n) {
    cc[n] = (w * NF + n) * 16 + llo;
    bv[n] = bias[cc[n]];
    if constexpr (ADDP) {
      u0[n] = W1p[cc[n]];
      u1[n] = W1p[NCOLS + cc[n]];
      u2[n] = W1p[2 * NCOLS + cc[n]];
    } else { u0[n] = u1[n] = u2[n] = 0.f; }
  }
#pragma unroll
  for (int m = 0; m < 2; ++m)
#pragma unroll
    for (int j = 0; j < 4; ++j) {
      int r = row0 + m * 16 + lhi * 4 + j;
      float px = 0.f, py = 0.f, pz = 0.f;
      if constexpr (ADDP) { px = pos[3*r]; py = pos[3*r+1]; pz = pos[3*r+2]; }
#pragma unroll
      for (int n = 0; n < NF; ++n) {
        float v = acc[m][n][j] + bv[n];
        if constexpr (ADDP) v += px * u0[n] + py * u1[n] + pz * u2[n];
        if (ACT == 1) v = fmaxf(v, 0.0f);
        if constexpr (OUTBF)
          ((short*)outp)[(size_t)r * NCOLS + cc[n]] = f2bf(v);
        else
          ((float*)outp)[(size_t)r * NCOLS + cc[n]] = v;
      }
    }
}

// ---------------------------------------------------------------------------
// MFMA conv: block = 4 targets (64 rows = 4 x 16 nbrs) x 256 cols, K=256.
// TU gathered as bf16 (half the bytes of r15); hout written bf16.
// ---------------------------------------------------------------------------
__global__ __launch_bounds__(256) void conv_mfma(
    const short* __restrict__ TU,    // bf16 [NPTS][256]
    const float* __restrict__ pos,
    const int* __restrict__ idx,
    const float* __restrict__ W1p,
    const short* __restrict__ w2f,
    const float* __restrict__ b2,
    short* __restrict__ hout) {      // bf16 [NPTS][256]
  __shared__ __align__(16) short m1s[64 * 256];
  __shared__ float Ub[4][256];
  __shared__ int js[64];

  int tid = threadIdx.x;
  int t0 = blockIdx.x * 4;
  if (tid < 64) js[tid] = idx[(t0 + (tid >> 4)) * 16 + (tid & 15)];
#pragma unroll
  for (int q = 0; q < 4; ++q) {
    int e = tid + 256 * q;
    int tg = e >> 8, c = e & 255;
    float x = pos[3 * (t0 + tg)], y = pos[3 * (t0 + tg) + 1],
          z = pos[3 * (t0 + tg) + 2];
    Ub[tg][c] = x * W1p[c] + y * W1p[256 + c] + z * W1p[512 + c];
  }
  __syncthreads();

  {
    int row = tid & 63;
    int wq = tid >> 6;
    int jrow = js[row];
    const short* TUj = TU + (size_t)jrow * 256;
    const float* Ui = &Ub[row >> 4][0];
#pragma unroll
    for (int q = 0; q < 8; ++q) {
      int c0 = wq * 8 + q * 32;
      bf16x8 tv = *reinterpret_cast<const bf16x8*>(TUj + c0);
      float4 ua = *reinterpret_cast<const float4*>(Ui + c0);
      float4 ub = *reinterpret_cast<const float4*>(Ui + c0 + 4);
      bf16x8 o;
      o[0] = f2bf(fmaxf(bf2f(tv[0]) - ua.x, 0.f));
      o[1] = f2bf(fmaxf(bf2f(tv[1]) - ua.y, 0.f));
      o[2] = f2bf(fmaxf(bf2f(tv[2]) - ua.z, 0.f));
      o[3] = f2bf(fmaxf(bf2f(tv[3]) - ua.w, 0.f));
      o[4] = f2bf(fmaxf(bf2f(tv[4]) - ub.x, 0.f));
      o[5] = f2bf(fmaxf(bf2f(tv[5]) - ub.y, 0.f));
      o[6] = f2bf(fmaxf(bf2f(tv[6]) - ub.z, 0.f));
      o[7] = f2bf(fmaxf(bf2f(tv[7]) - ub.w, 0.f));
      int byte = row * 512 + c0 * 2;
      byte ^= (row & 7) << 4;
      *reinterpret_cast<bf16x8*>(reinterpret_cast<char*>(m1s) + byte) = o;
    }
  }
  __syncthreads();

  int l = tid & 63, w = tid >> 6;
  int lhi = l >> 4, llo = l & 15;
  f32x4 zero = {0.f, 0.f, 0.f, 0.f};
  f32x4 acc[4][4];
#pragma unroll
  for (int m = 0; m < 4; ++m)
#pragma unroll
    for (int n = 0; n < 4; ++n) acc[m][n] = zero;

  const bf16x8* Wf = reinterpret_cast<const bf16x8*>(w2f);
#pragma unroll
  for (int ks = 0; ks < 8; ++ks) {
    int k0 = ks * 32;
    bf16x8 af[4], bfr[4];
#pragma unroll
    for (int m = 0; m < 4; ++m) {
      int r = m * 16 + llo;
      int byte = r * 512 + k0 * 2 + lhi * 16;
      byte ^= (r & 7) << 4;
      af[m] = *reinterpret_cast<const bf16x8*>(
          reinterpret_cast<const char*>(m1s) + byte);
    }
#pragma unroll
    for (int n = 0; n < 4; ++n)
      bfr[n] = Wf[((w * 4 + n) * 8 + ks) * 64 + l];
#pragma unroll
    for (int m = 0; m < 4; ++m)
#pragma unroll
      for (int n = 0; n < 4; ++n)
        acc[m][n] = __builtin_amdgcn_mfma_f32_16x16x32_bf16(af[m], bfr[n],
                                                            acc[m][n], 0, 0, 0);
  }

#pragma unroll
  for (int m = 0; m < 4; ++m)
#pragma unroll
    for (int n = 0; n < 4; ++n) {
      float v = fmaxf(fmaxf(acc[m][n][0], acc[m][n][1]),
                      fmaxf(acc[m][n][2], acc[m][n][3]));
      v = fmaxf(v, __shfl_xor(v, 16));
      v = fmaxf(v, __shfl_xor(v, 32));
      if (lhi == 0) {
        int c = w * 64 + n * 16 + llo;
        hout[(size_t)(t0 + m) * CDIM + c] = f2bf(fmaxf(v + b2[c], 0.0f));
      }
    }
}

// ---------------------------------------------------------------------------
// Final layer: out[r] = sigmoid(h2[r] . w3 + b3); one wave per row (h2 f32).
// ---------------------------------------------------------------------------
__global__ __launch_bounds__(64) void final_k(const float* __restrict__ h2,
                                              const float* __restrict__ w3,
                                              const float* __restrict__ b3,
                                              float* __restrict__ out) {
  int r = blockIdx.x, l = threadIdx.x;
  float s = h2[(size_t)r * HDIM + l] * w3[l] +
            h2[(size_t)r * HDIM + 64 + l] * w3[64 + l];
#pragma unroll
  for (int o = 32; o > 0; o >>= 1) s += __shfl_down(s, o);
  if (l == 0) out[r] = 1.0f / (1.0f + expf(-(s + b3[0])));
}

extern "C" void kernel_launch(void* const* d_in, const int* in_sizes, int n_in,
                              void* d_out, int out_size, void* d_ws,
                              size_t ws_size, hipStream_t stream) {
  const float* pos   = (const float*)d_in[0];
  const float* c1_W1 = (const float*)d_in[1];
  const float* c1_b1 = (const float*)d_in[2];
  const float* c1_W2 = (const float*)d_in[3];
  const float* c1_b2 = (const float*)d_in[4];
  const float* c2_W1 = (const float*)d_in[5];
  const float* c2_b1 = (const float*)d_in[6];
  const float* c2_W2 = (const float*)d_in[7];
  const float* c2_b2 = (const float*)d_in[8];
  const float* c3_W1 = (const float*)d_in[9];
  const float* c3_b1 = (const float*)d_in[10];
  const float* c3_W2 = (const float*)d_in[11];
  const float* c3_b2 = (const float*)d_in[12];
  const float* h_W1  = (const float*)d_in[13];
  const float* h_b1  = (const float*)d_in[14];
  const float* h_W2  = (const float*)d_in[15];
  const float* h_b2  = (const float*)d_in[16];
  const float* h_W3  = (const float*)d_in[17];
  const float* h_b3  = (const float*)d_in[18];
  float* out = (float*)d_out;

  char* w = (char*)d_ws;
  const size_t MB = 1 << 20;
  const size_t KB = 1 << 10;
  int*      p_idx  = (int*)w;                           // 512K
  float4*   p_pos4 = (float4*)(w + 512 * KB);           // 128K
  unsigned* p_T    = (unsigned*)(w + 640 * KB);         // 32K
  unsigned* p_cnt  = (unsigned*)(w + 672 * KB);         // 32K
  short*    p_w2f1 = (short*)(w + 704 * KB);            // 128K
  short*    p_w2f2 = (short*)(w + 832 * KB);            // 128K
  short*    p_w2f3 = (short*)(w + 960 * KB);            // 128K
  short*    p_wc2a = (short*)(w + 1088 * KB);           // 128K
  short*    p_wc3a = (short*)(w + 1216 * KB);           // 128K
  short*    p_whW1 = (short*)(w + 1344 * KB);           // 64K
  short*    p_whW2 = (short*)(w + 1408 * KB);           // 32K
  u64*      p_cbuf = (u64*)(w + 1536 * KB);             // 3MB
  short*    p_TU   = (short*)(w + 5 * MB);              // 4MB  [5,9)
  short*    p_c1   = (short*)(w + 9 * MB);              // 2MB  [9,11)
  unsigned* p_v    = (unsigned*)(w + 13 * MB);          // 16MB [13,29) knn only
  short*    p_hA   = (short*)(w + 13 * MB);             // 4MB  (v dead)
  short*    p_hB   = (short*)(w + 21 * MB);             // 4MB  (v dead)
  float*    p_c2   = (float*)(w + 29 * MB);             // 4MB

  // fused prep: weights, pos4, conv1 TU (bf16; region untouched by kNN)
  prep_all<<<2016, 256, 0, stream>>>(
      c1_W2, c2_W2, c3_W2, c2_W1, c3_W1, h_W1, h_W2,
      p_w2f1, p_w2f2, p_w2f3, p_wc2a, p_wc3a, p_whW1, p_whW2,
      pos, p_pos4, c1_W1, c1_b1, p_TU);

  // kNN: two-pass exact top-16 (wave-parallel merge, static-shift advance)
  knn_d2p1<<<(NPTS / 256) * NCH, 256, 0, stream>>>(p_pos4, p_v);
  knn_merge<<<NPTS / 4, 256, 0, stream>>>(p_v, p_T, p_cnt);
  knn_d2p2<<<(NPTS / 256) * NCH, 256, 0, stream>>>(p_pos4, p_T, p_cnt, p_cbuf);
  knn_select<<<NPTS / 256, 256, 0, stream>>>(p_cnt, p_cbuf, p_idx);

  // conv1
  conv_mfma<<<NPTS / 4, 256, 0, stream>>>(p_TU, pos, p_idx, c1_W1 + 3 * 256,
                                          p_w2f1, c1_b2, p_hA);
  // conv2
  gemm_mfma<256, 256, 0, 1, 1><<<NPTS / 32, 256, 0, stream>>>(
      p_hA, p_wc2a, c2_b1, pos, c2_W1 + 256 * 256, p_TU);
  conv_mfma<<<NPTS / 4, 256, 0, stream>>>(p_TU, pos, p_idx, c2_W1 + 256 * 256,
                                          p_w2f2, c2_b2, p_hB);
  // conv3
  gemm_mfma<256, 256, 0, 1, 1><<<NPTS / 32, 256, 0, stream>>>(
      p_hB, p_wc3a, c3_b1, pos, c3_W1 + 256 * 256, p_TU);
  conv_mfma<<<NPTS / 4, 256, 0, stream>>>(p_TU, pos, p_idx, c3_W1 + 256 * 256,
                                          p_w2f3, c3_b2, p_hA);
  // classifier
  gemm_mfma<128, 256, 1, 0, 1><<<NPTS / 32, 256, 0, stream>>>(
      p_hA, p_whW1, h_b1, nullptr, nullptr, p_c1);
  gemm_mfma<128, 128, 1, 0, 0><<<NPTS / 32, 256, 0, stream>>>(
      p_c1, p_whW2, h_b2, nullptr, nullptr, p_c2);
  final_k<<<NPTS, 64, 0, stream>>>(p_c2, h_W3, h_b3, out);

  (void)in_sizes; (void)n_in; (void)out_size; (void)ws_size;
}

// Round 17
// 252.492 us; speedup vs baseline: 1.4872x; 1.0037x over previous
//
#include <hip/hip_runtime.h>
#include <hip/hip_bf16.h>
#include <math.h>

#define NPTS 8192
#define CDIM 256
#define HDIM 128
#define NCH  32
#define CH   (NPTS / NCH)     // 256 candidates per chunk
#define CAP  48               // qualifier buffer slots per target

typedef __attribute__((ext_vector_type(8))) short bf16x8;
typedef __attribute__((ext_vector_type(4))) float f32x4;
typedef unsigned long long u64;

static __device__ __forceinline__ short f2bf(float f) {
  __hip_bfloat16 h = __float2bfloat16(f);
  return *reinterpret_cast<short*>(&h);
}
static __device__ __forceinline__ float bf2f(short s) {
  return __uint_as_float(((unsigned)(unsigned short)s) << 16);
}

// median-of-3: one VALU op; med3(lo, key, hi) == min(max(lo,key),hi) for lo<=hi
static __device__ __forceinline__ unsigned umed3(unsigned a, unsigned b,
                                                 unsigned c) {
  unsigned d;
  asm("v_med3_u32 %0, %1, %2, %3" : "=v"(d) : "v"(a), "v"(b), "v"(c));
  return d;
}

// Bit-exact d2 key shared by both kNN passes.
static __device__ __forceinline__ unsigned d2key(float4 p, float4 c) {
  float dot = fmaf(p.x, c.x, fmaf(p.y, c.y, p.z * c.z));
  float d2 = fmaf(-2.0f, dot, p.w + c.w);
  return __float_as_uint(fmaxf(d2, 0.0f));
}

#define U32INIT unsigned b0=~0u,b1=~0u,b2=~0u,b3=~0u,b4=~0u,b5=~0u,b6=~0u, \
                         b7=~0u,b8=~0u,b9=~0u,b10=~0u,b11=~0u,b12=~0u, \
                         b13=~0u,b14=~0u,b15=~0u;
#define U32CHAIN(key) { \
  b15 = umed3(b14, key, b15); b14 = umed3(b13, key, b14); \
  b13 = umed3(b12, key, b13); b12 = umed3(b11, key, b12); \
  b11 = umed3(b10, key, b11); b10 = umed3(b9,  key, b10); \
  b9  = umed3(b8,  key, b9);  b8  = umed3(b7,  key, b8);  \
  b7  = umed3(b6,  key, b7);  b6  = umed3(b5,  key, b6);  \
  b5  = umed3(b4,  key, b5);  b4  = umed3(b3,  key, b4);  \
  b3  = umed3(b2,  key, b3);  b2  = umed3(b1,  key, b2);  \
  b1  = umed3(b0,  key, b1);  b0  = min(b0, key); }

#define KSTEP(s) { bool sw_ = key < k##s; u64 t_ = k##s; \
                   k##s = sw_ ? key : t_; key = sw_ ? t_ : key; }
#define KCHAIN KSTEP(0) KSTEP(1) KSTEP(2) KSTEP(3) KSTEP(4) KSTEP(5) \
               KSTEP(6) KSTEP(7) KSTEP(8) KSTEP(9) KSTEP(10) KSTEP(11) \
               KSTEP(12) KSTEP(13) KSTEP(14) KSTEP(15)
#define KINIT u64 k0=~0ULL,k1=~0ULL,k2=~0ULL,k3=~0ULL,k4=~0ULL,k5=~0ULL, \
                  k6=~0ULL,k7=~0ULL,k8=~0ULL,k9=~0ULL,k10=~0ULL,k11=~0ULL, \
                  k12=~0ULL,k13=~0ULL,k14=~0ULL,k15=~0ULL;

// ---------------------------------------------------------------------------
// Fused prep: 7 fragment-major bf16 weight conversions + pos4 + conv1 TU
// (TU stored bf16).
// ---------------------------------------------------------------------------
__global__ __launch_bounds__(256) void prep_all(
    const float* __restrict__ c1W2, const float* __restrict__ c2W2,
    const float* __restrict__ c3W2, const float* __restrict__ c2W1,
    const float* __restrict__ c3W1, const float* __restrict__ hW1,
    const float* __restrict__ hW2,
    short* __restrict__ w2f1, short* __restrict__ w2f2,
    short* __restrict__ w2f3, short* __restrict__ wc2a,
    short* __restrict__ wc3a, short* __restrict__ whW1,
    short* __restrict__ whW2,
    const float* __restrict__ pos, float4* __restrict__ pos4,
    const float* __restrict__ c1W1, const float* __restrict__ c1b1,
    short* __restrict__ TU) {
  int b = blockIdx.x, tid = threadIdx.x;
  if (b < 1280) {                 // 256x256 weights, KS=8
    const float* W; short* wf; int rb;
    if (b < 256)       { W = c1W2; wf = w2f1; rb = b; }
    else if (b < 512)  { W = c2W2; wf = w2f2; rb = b - 256; }
    else if (b < 768)  { W = c3W2; wf = w2f3; rb = b - 512; }
    else if (b < 1024) { W = c2W1; wf = wc2a; rb = b - 768; }
    else               { W = c3W1; wf = wc3a; rb = b - 1024; }
    int t = rb * 256 + tid;
    int q = t & 7, l = (t >> 3) & 63, F = t >> 9;
    int ks = F & 7, c16 = F >> 3;
    int k = ks * 32 + ((l >> 4) << 3) + q;
    int c = c16 * 16 + (l & 15);
    wf[t] = f2bf(W[k * 256 + c]);
  } else if (b < 1408) {          // h_W1: KDIM 256 (KS=8), NCOLS 128
    int t = (b - 1280) * 256 + tid;
    int q = t & 7, l = (t >> 3) & 63, F = t >> 9;
    int ks = F & 7, c16 = F >> 3;
    int k = ks * 32 + ((l >> 4) << 3) + q;
    int c = c16 * 16 + (l & 15);
    whW1[t] = f2bf(hW1[k * 128 + c]);
  } else if (b < 1472) {          // h_W2: KDIM 128 (KS=4), NCOLS 128
    int t = (b - 1408) * 256 + tid;
    int q = t & 7, l = (t >> 3) & 63, F = t >> 9;
    int ks = F & 3, c16 = F >> 2;
    int k = ks * 32 + ((l >> 4) << 3) + q;
    int c = c16 * 16 + (l & 15);
    whW2[t] = f2bf(hW2[k * 128 + c]);
  } else if (b < 1504) {          // pos4
    int i = (b - 1472) * 256 + tid;
    float x = pos[3 * i], y = pos[3 * i + 1], z = pos[3 * i + 2];
    pos4[i] = make_float4(x, y, z, x * x + y * y + z * z);
  } else {                        // conv1 TU (bf16): b1 + pos.(W1h+W1p)
    int c = tid;
    float w0 = c1W1[c]       + c1W1[768 + c];
    float w1 = c1W1[256 + c] + c1W1[1024 + c];
    float w2 = c1W1[512 + c] + c1W1[1280 + c];
    float bv = c1b1[c];
    int i0 = (b - 1504) * 16;
#pragma unroll
    for (int r = 0; r < 16; ++r) {
      int i = i0 + r;
      float x = pos[3 * i], y = pos[3 * i + 1], z = pos[3 * i + 2];
      TU[(size_t)i * 256 + c] = f2bf(fmaf(x, w0, fmaf(y, w1, fmaf(z, w2, bv))));
    }
  }
}

// ---------------------------------------------------------------------------
// kNN pass 1: thread = (target i, chunk ch). Candidates read directly from
// L2-resident pos4 at BLOCK-UNIFORM addresses -> scalar s_load broadcasts
// (no LDS staging, no barriers, scalar pipe overlaps the med3 VALU chain).
// ---------------------------------------------------------------------------
__global__ __launch_bounds__(256) void knn_d2p1(const float4* __restrict__ pos4,
                                                unsigned* __restrict__ v) {
  int ch = blockIdx.x & (NCH - 1);
  int i  = (blockIdx.x >> 5) * 256 + threadIdx.x;
  const float4* cb = pos4 + ch * CH;   // block-uniform base

  float4 p = pos4[i];
  U32INIT
  for (int jj = 0; jj < CH; jj += 4) {
    float4 c0 = cb[jj], c1 = cb[jj + 1], c2 = cb[jj + 2], c3 = cb[jj + 3];
    unsigned x0 = d2key(p, c0), x1 = d2key(p, c1);
    unsigned x2 = d2key(p, c2), x3 = d2key(p, c3);
    U32CHAIN(x0) U32CHAIN(x1) U32CHAIN(x2) U32CHAIN(x3)
  }
  uint4* dst = reinterpret_cast<uint4*>(v + ((size_t)ch * NPTS + i) * 16);
  dst[0] = make_uint4(b0, b1, b2, b3);
  dst[1] = make_uint4(b4, b5, b6, b7);
  dst[2] = make_uint4(b8, b9, b10, b11);
  dst[3] = make_uint4(b12, b13, b14, b15);
}

// ---------------------------------------------------------------------------
// kNN merge: one WAVE per target; 16 selection rounds, static register-shift
// advance (rule #20 safe). Exact global 16th -> T[i].
// ---------------------------------------------------------------------------
__global__ __launch_bounds__(256) void knn_merge(const unsigned* __restrict__ v,
                                                 unsigned* __restrict__ T,
                                                 unsigned* __restrict__ cnt) {
  int wv = threadIdx.x >> 6, lane = threadIdx.x & 63;
  int i = blockIdx.x * 4 + wv;
  int ch = lane >> 1, half = lane & 1;
  const uint4* src = reinterpret_cast<const uint4*>(
      v + ((size_t)ch * NPTS + i) * 16 + half * 8);
  uint4 a = src[0], b = src[1];
  unsigned r1 = a.y, r2 = a.z, r3 = a.w;
  unsigned r4 = b.x, r5 = b.y, r6 = b.z, r7 = b.w;
  unsigned h = a.x;
  unsigned wmin = 0;
#pragma unroll
  for (int round = 0; round < 16; ++round) {
    unsigned m = h;
    m = min(m, (unsigned)__shfl_xor((int)m, 1));
    m = min(m, (unsigned)__shfl_xor((int)m, 2));
    m = min(m, (unsigned)__shfl_xor((int)m, 4));
    m = min(m, (unsigned)__shfl_xor((int)m, 8));
    m = min(m, (unsigned)__shfl_xor((int)m, 16));
    m = min(m, (unsigned)__shfl_xor((int)m, 32));
    wmin = m;
    u64 ball = __ballot(h == m);
    bool adv = (lane == __ffsll(ball) - 1);
    h  = adv ? r1 : h;
    r1 = adv ? r2 : r1;
    r2 = adv ? r3 : r2;
    r3 = adv ? r4 : r3;
    r4 = adv ? r5 : r4;
    r5 = adv ? r6 : r5;
    r6 = adv ? r7 : r6;
    r7 = adv ? 0xFFFFFFFFu : r7;
  }
  if (lane == 0) { T[i] = wmin; cnt[i] = 0; }
}

// ---------------------------------------------------------------------------
// kNN pass 2: 8x-unrolled re-scan with uniform scalar candidate loads
// (identical d2key bits); min8 guard, rare qualifier append.
// ---------------------------------------------------------------------------
__global__ __launch_bounds__(256) void knn_d2p2(const float4* __restrict__ pos4,
                                                const unsigned* __restrict__ T,
                                                unsigned* __restrict__ cnt,
                                                u64* __restrict__ cbuf) {
  int ch = blockIdx.x & (NCH - 1);
  int i  = (blockIdx.x >> 5) * 256 + threadIdx.x;
  const float4* cb = pos4 + ch * CH;   // block-uniform base

  float4 p = pos4[i];
  unsigned Ti = T[i];
  int jb = ch * CH;
  for (int jj = 0; jj < CH; jj += 8) {
    unsigned k[8];
#pragma unroll
    for (int u = 0; u < 8; ++u) k[u] = d2key(p, cb[jj + u]);
    unsigned m = min(min(min(k[0], k[1]), min(k[2], k[3])),
                     min(min(k[4], k[5]), min(k[6], k[7])));
    if (m <= Ti) {
#pragma unroll
      for (int u = 0; u < 8; ++u) {
        if (k[u] <= Ti) {
          unsigned slot = atomicAdd(&cnt[i], 1u);
          if (slot < CAP)
            cbuf[(size_t)i * CAP + slot] =
                ((u64)k[u] << 32) | (unsigned)(jb + jj + u);
        }
      }
    }
  }
}

// ---------------------------------------------------------------------------
// kNN select: exact lexicographic (d2, idx) top-16 over the <=CAP qualifiers.
// ---------------------------------------------------------------------------
__global__ __launch_bounds__(256) void knn_select(const unsigned* __restrict__ cnt,
                                                  const u64* __restrict__ cbuf,
                                                  int* __restrict__ idx_out) {
  int i = blockIdx.x * 256 + threadIdx.x;
  int c = (int)min(cnt[i], (unsigned)CAP);
  KINIT
#pragma unroll 1
  for (int q = 0; q < c; ++q) {
    u64 key = cbuf[(size_t)i * CAP + q];
    if (key < k15) { KCHAIN }
  }
  int* o = idx_out + i * 16;
  o[0]=(int)(unsigned)k0;   o[1]=(int)(unsigned)k1;   o[2]=(int)(unsigned)k2;
  o[3]=(int)(unsigned)k3;   o[4]=(int)(unsigned)k4;   o[5]=(int)(unsigned)k5;
  o[6]=(int)(unsigned)k6;   o[7]=(int)(unsigned)k7;   o[8]=(int)(unsigned)k8;
  o[9]=(int)(unsigned)k9;   o[10]=(int)(unsigned)k10; o[11]=(int)(unsigned)k11;
  o[12]=(int)(unsigned)k12; o[13]=(int)(unsigned)k13; o[14]=(int)(unsigned)k14;
  o[15]=(int)(unsigned)k15;
}

// ---------------------------------------------------------------------------
// MFMA GEMM: out = act(A_bf16 @ Wf + bias [+ pos@W1p]).
// A is bf16 -> staging is a pure swizzled copy. OUTBF selects bf16/f32 out.
// ---------------------------------------------------------------------------
template <int NCOLS, int KDIM, int ACT, int ADDP, int OUTBF>
__global__ __launch_bounds__(256) void gemm_mfma(
    const short* __restrict__ A,
    const short* __restrict__ wf,
    const float* __restrict__ bias,
    const float* __restrict__ pos,
    const float* __restrict__ W1p,
    void* __restrict__ outp) {
  constexpr int KS = KDIM / 32;
  constexpr int NF = NCOLS / 64;
  __shared__ __align__(16) short As[32 * KDIM];

  int tid = threadIdx.x;
  int row0 = blockIdx.x * 32;

  {  // stage A: 32 rows x KDIM bf16 -> swizzled LDS (pure copy)
    int row = tid & 31, wq = tid >> 5;
    const short* Ar = A + (size_t)(row0 + row) * KDIM;
#pragma unroll
    for (int q = 0; q < KDIM / 64; ++q) {
      int c0 = wq * 8 + q * 64;
      bf16x8 o = *reinterpret_cast<const bf16x8*>(Ar + c0);
      int byte = row * (KDIM * 2) + c0 * 2;
      byte ^= (row & 7) << 4;
      *reinterpret_cast<bf16x8*>(reinterpret_cast<char*>(As) + byte) = o;
    }
  }
  __syncthreads();

  int l = tid & 63, w = tid >> 6;
  int lhi = l >> 4, llo = l & 15;
  f32x4 zero = {0.f, 0.f, 0.f, 0.f};
  f32x4 acc[2][NF];
#pragma unroll
  for (int m = 0; m < 2; ++m)
#pragma unroll
    for (int n = 0; n < NF; ++n) acc[m][n] = zero;

  const bf16x8* WfV = reinterpret_cast<const bf16x8*>(wf);
#pragma unroll
  for (int ks = 0; ks < KS; ++ks) {
    bf16x8 af[2], bfr[NF];
#pragma unroll
    for (int m = 0; m < 2; ++m) {
      int r = m * 16 + llo;
      int byte = r * (KDIM * 2) + ks * 64 + lhi * 16;
      byte ^= (r & 7) << 4;
      af[m] = *reinterpret_cast<const bf16x8*>(
          reinterpret_cast<const char*>(As) + byte);
    }
#pragma unroll
    for (int n = 0; n < NF; ++n)
      bfr[n] = WfV[((w * NF + n) * KS + ks) * 64 + l];
#pragma unroll
    for (int m = 0; m < 2; ++m)
#pragma unroll
      for (int n = 0; n < NF; ++n)
        acc[m][n] = __builtin_amdgcn_mfma_f32_16x16x32_bf16(af[m], bfr[n],
                                                            acc[m][n], 0, 0, 0);
  }

  int cc[NF];
  float bv[NF], u0[NF], u1[NF], u2[NF];
#pragma unroll
  for (int n = 0; n < NF; ++n) {
    cc[n] = (w * NF + n) * 16 + llo;
    bv[n] = bias[cc[n]];
    if constexpr (ADDP) {
      u0[n] = W1p[cc[n]];
      u1[n] = W1p[NCOLS + cc[n]];
      u2[n] = W1p[2 * NCOLS + cc[n]];
    } else { u0[n] = u1[n] = u2[n] = 0.f; }
  }
#pragma unroll
  for (int m = 0; m < 2; ++m)
#pragma unroll
    for (int j = 0; j < 4; ++j) {
      int r = row0 + m * 16 + lhi * 4 + j;
      float px = 0.f, py = 0.f, pz = 0.f;
      if constexpr (ADDP) { px = pos[3*r]; py = pos[3*r+1]; pz = pos[3*r+2]; }
#pragma unroll
      for (int n = 0; n < NF; ++n) {
        float v = acc[m][n][j] + bv[n];
        if constexpr (ADDP) v += px * u0[n] + py * u1[n] + pz * u2[n];
        if (ACT == 1) v = fmaxf(v, 0.0f);
        if constexpr (OUTBF)
          ((short*)outp)[(size_t)r * NCOLS + cc[n]] = f2bf(v);
        else
          ((float*)outp)[(size_t)r * NCOLS + cc[n]] = v;
      }
    }
}

// ---------------------------------------------------------------------------
// MFMA conv: block = 4 targets (64 rows = 4 x 16 nbrs) x 256 cols, K=256.
// TU gathered as bf16; hout written bf16.
// ---------------------------------------------------------------------------
__global__ __launch_bounds__(256) void conv_mfma(
    const short* __restrict__ TU,    // bf16 [NPTS][256]
    const float* __restrict__ pos,
    const int* __restrict__ idx,
    const float* __restrict__ W1p,
    const short* __restrict__ w2f,
    const float* __restrict__ b2,
    short* __restrict__ hout) {      // bf16 [NPTS][256]
  __shared__ __align__(16) short m1s[64 * 256];
  __shared__ float Ub[4][256];
  __shared__ int js[64];

  int tid = threadIdx.x;
  int t0 = blockIdx.x * 4;
  if (tid < 64) js[tid] = idx[(t0 + (tid >> 4)) * 16 + (tid & 15)];
#pragma unroll
  for (int q = 0; q < 4; ++q) {
    int e = tid + 256 * q;
    int tg = e >> 8, c = e & 255;
    float x = pos[3 * (t0 + tg)], y = pos[3 * (t0 + tg) + 1],
          z = pos[3 * (t0 + tg) + 2];
    Ub[tg][c] = x * W1p[c] + y * W1p[256 + c] + z * W1p[512 + c];
  }
  __syncthreads();

  {
    int row = tid & 63;
    int wq = tid >> 6;
    int jrow = js[row];
    const short* TUj = TU + (size_t)jrow * 256;
    const float* Ui = &Ub[row >> 4][0];
#pragma unroll
    for (int q = 0; q < 8; ++q) {
      int c0 = wq * 8 + q * 32;
      bf16x8 tv = *reinterpret_cast<const bf16x8*>(TUj + c0);
      float4 ua = *reinterpret_cast<const float4*>(Ui + c0);
      float4 ub = *reinterpret_cast<const float4*>(Ui + c0 + 4);
      bf16x8 o;
      o[0] = f2bf(fmaxf(bf2f(tv[0]) - ua.x, 0.f));
      o[1] = f2bf(fmaxf(bf2f(tv[1]) - ua.y, 0.f));
      o[2] = f2bf(fmaxf(bf2f(tv[2]) - ua.z, 0.f));
      o[3] = f2bf(fmaxf(bf2f(tv[3]) - ua.w, 0.f));
      o[4] = f2bf(fmaxf(bf2f(tv[4]) - ub.x, 0.f));
      o[5] = f2bf(fmaxf(bf2f(tv[5]) - ub.y, 0.f));
      o[6] = f2bf(fmaxf(bf2f(tv[6]) - ub.z, 0.f));
      o[7] = f2bf(fmaxf(bf2f(tv[7]) - ub.w, 0.f));
      int byte = row * 512 + c0 * 2;
      byte ^= (row & 7) << 4;
      *reinterpret_cast<bf16x8*>(reinterpret_cast<char*>(m1s) + byte) = o;
    }
  }
  __syncthreads();

  int l = tid & 63, w = tid >> 6;
  int lhi = l >> 4, llo = l & 15;
  f32x4 zero = {0.f, 0.f, 0.f, 0.f};
  f32x4 acc[4][4];
#pragma unroll
  for (int m = 0; m < 4; ++m)
#pragma unroll
    for (int n = 0; n < 4; ++n) acc[m][n] = zero;

  const bf16x8* Wf = reinterpret_cast<const bf16x8*>(w2f);
#pragma unroll
  for (int ks = 0; ks < 8; ++ks) {
    int k0 = ks * 32;
    bf16x8 af[4], bfr[4];
#pragma unroll
    for (int m = 0; m < 4; ++m) {
      int r = m * 16 + llo;
      int byte = r * 512 + k0 * 2 + lhi * 16;
      byte ^= (r & 7) << 4;
      af[m] = *reinterpret_cast<const bf16x8*>(
          reinterpret_cast<const char*>(m1s) + byte);
    }
#pragma unroll
    for (int n = 0; n < 4; ++n)
      bfr[n] = Wf[((w * 4 + n) * 8 + ks) * 64 + l];
#pragma unroll
    for (int m = 0; m < 4; ++m)
#pragma unroll
      for (int n = 0; n < 4; ++n)
        acc[m][n] = __builtin_amdgcn_mfma_f32_16x16x32_bf16(af[m], bfr[n],
                                                            acc[m][n], 0, 0, 0);
  }

#pragma unroll
  for (int m = 0; m < 4; ++m)
#pragma unroll
    for (int n = 0; n < 4; ++n) {
      float v = fmaxf(fmaxf(acc[m][n][0], acc[m][n][1]),
                      fmaxf(acc[m][n][2], acc[m][n][3]));
      v = fmaxf(v, __shfl_xor(v, 16));
      v = fmaxf(v, __shfl_xor(v, 32));
      if (lhi == 0) {
        int c = w * 64 + n * 16 + llo;
        hout[(size_t)(t0 + m) * CDIM + c] = f2bf(fmaxf(v + b2[c], 0.0f));
      }
    }
}

// ---------------------------------------------------------------------------
// Final layer: out[r] = sigmoid(h2[r] . w3 + b3); one wave per row (h2 f32).
// ---------------------------------------------------------------------------
__global__ __launch_bounds__(64) void final_k(const float* __restrict__ h2,
                                              const float* __restrict__ w3,
                                              const float* __restrict__ b3,
                                              float* __restrict__ out) {
  int r = blockIdx.x, l = threadIdx.x;
  float s = h2[(size_t)r * HDIM + l] * w3[l] +
            h2[(size_t)r * HDIM + 64 + l] * w3[64 + l];
#pragma unroll
  for (int o = 32; o > 0; o >>= 1) s += __shfl_down(s, o);
  if (l == 0) out[r] = 1.0f / (1.0f + expf(-(s + b3[0])));
}

extern "C" void kernel_launch(void* const* d_in, const int* in_sizes, int n_in,
                              void* d_out, int out_size, void* d_ws,
                              size_t ws_size, hipStream_t stream) {
  const float* pos   = (const float*)d_in[0];
  const float* c1_W1 = (const float*)d_in[1];
  const float* c1_b1 = (const float*)d_in[2];
  const float* c1_W2 = (const float*)d_in[3];
  const float* c1_b2 = (const float*)d_in[4];
  const float* c2_W1 = (const float*)d_in[5];
  const float* c2_b1 = (const float*)d_in[6];
  const float* c2_W2 = (const float*)d_in[7];
  const float* c2_b2 = (const float*)d_in[8];
  const float* c3_W1 = (const float*)d_in[9];
  const float* c3_b1 = (const float*)d_in[10];
  const float* c3_W2 = (const float*)d_in[11];
  const float* c3_b2 = (const float*)d_in[12];
  const float* h_W1  = (const float*)d_in[13];
  const float* h_b1  = (const float*)d_in[14];
  const float* h_W2  = (const float*)d_in[15];
  const float* h_b2  = (const float*)d_in[16];
  const float* h_W3  = (const float*)d_in[17];
  const float* h_b3  = (const float*)d_in[18];
  float* out = (float*)d_out;

  char* w = (char*)d_ws;
  const size_t MB = 1 << 20;
  const size_t KB = 1 << 10;
  int*      p_idx  = (int*)w;                           // 512K
  float4*   p_pos4 = (float4*)(w + 512 * KB);           // 128K
  unsigned* p_T    = (unsigned*)(w + 640 * KB);         // 32K
  unsigned* p_cnt  = (unsigned*)(w + 672 * KB);         // 32K
  short*    p_w2f1 = (short*)(w + 704 * KB);            // 128K
  short*    p_w2f2 = (short*)(w + 832 * KB);            // 128K
  short*    p_w2f3 = (short*)(w + 960 * KB);            // 128K
  short*    p_wc2a = (short*)(w + 1088 * KB);           // 128K
  short*    p_wc3a = (short*)(w + 1216 * KB);           // 128K
  short*    p_whW1 = (short*)(w + 1344 * KB);           // 64K
  short*    p_whW2 = (short*)(w + 1408 * KB);           // 32K
  u64*      p_cbuf = (u64*)(w + 1536 * KB);             // 3MB
  short*    p_TU   = (short*)(w + 5 * MB);              // 4MB  [5,9)
  short*    p_c1   = (short*)(w + 9 * MB);              // 2MB  [9,11)
  unsigned* p_v    = (unsigned*)(w + 13 * MB);          // 16MB [13,29) knn only
  short*    p_hA   = (short*)(w + 13 * MB);             // 4MB  (v dead)
  short*    p_hB   = (short*)(w + 21 * MB);             // 4MB  (v dead)
  float*    p_c2   = (float*)(w + 29 * MB);             // 4MB

  // fused prep: weights, pos4, conv1 TU (bf16; region untouched by kNN)
  prep_all<<<2016, 256, 0, stream>>>(
      c1_W2, c2_W2, c3_W2, c2_W1, c3_W1, h_W1, h_W2,
      p_w2f1, p_w2f2, p_w2f3, p_wc2a, p_wc3a, p_whW1, p_whW2,
      pos, p_pos4, c1_W1, c1_b1, p_TU);

  // kNN: two-pass exact top-16 (scalar-broadcast scans, static-shift merge)
  knn_d2p1<<<(NPTS / 256) * NCH, 256, 0, stream>>>(p_pos4, p_v);
  knn_merge<<<NPTS / 4, 256, 0, stream>>>(p_v, p_T, p_cnt);
  knn_d2p2<<<(NPTS / 256) * NCH, 256, 0, stream>>>(p_pos4, p_T, p_cnt, p_cbuf);
  knn_select<<<NPTS / 256, 256, 0, stream>>>(p_cnt, p_cbuf, p_idx);

  // conv1
  conv_mfma<<<NPTS / 4, 256, 0, stream>>>(p_TU, pos, p_idx, c1_W1 + 3 * 256,
                                          p_w2f1, c1_b2, p_hA);
  // conv2
  gemm_mfma<256, 256, 0, 1, 1><<<NPTS / 32, 256, 0, stream>>>(
      p_hA, p_wc2a, c2_b1, pos, c2_W1 + 256 * 256, p_TU);
  conv_mfma<<<NPTS / 4, 256, 0, stream>>>(p_TU, pos, p_idx, c2_W1 + 256 * 256,
                                          p_w2f2, c2_b2, p_hB);
  // conv3
  gemm_mfma<256, 256, 0, 1, 1><<<NPTS / 32, 256, 0, stream>>>(
      p_hB, p_wc3a, c3_b1, pos, c3_W1 + 256 * 256, p_TU);
  conv_mfma<<<NPTS / 4, 256, 0, stream>>>(p_TU, pos, p_idx, c3_W1 + 256 * 256,
                                          p_w2f3, c3_b2, p_hA);
  // classifier
  gemm_mfma<128, 256, 1, 0, 1><<<NPTS / 32, 256, 0, stream>>>(
      p_hA, p_whW1, h_b1, nullptr, nullptr, p_c1);
  gemm_mfma<128, 128, 1, 0, 0><<<NPTS / 32, 256, 0, stream>>>(
      p_c1, p_whW2, h_b2, nullptr, nullptr, p_c2);
  final_k<<<NPTS, 64, 0, stream>>>(p_c2, h_W3, h_b3, out);

  (void)in_sizes; (void)n_in; (void)out_size; (void)ws_size;
}